// Round 8
// baseline (451.066 us; speedup 1.0000x reference)
//
#include <hip/hip_runtime.h>

// GPT-2 block forward, MI355X/gfx950. B=4 T=2048 C=768 H=12 D=64; M=8192.
// R17: faithful m201 8-phase GEMM port (all four GEMMs):
//   256x256 tile, BK=64, 512 thr / 8 waves (2Mx4N, per-wave 128x64),
//   2-dbuf LDS (128 KiB), 4 phases/K-tile:
//     P1 {rd A m0-3 kk0 + B kk0; stage A-half0(t+1); bar; lgkmcnt0; prio;
//         16 MFMA} P2 {A kk1 + B kk1; stage A-half1(t+1); ...}
//     P3 {A m4-7 kk0, B from regs; stage B-half0(t+2)} P4 {A m4-7 kk1;
//         stage B-half1(t+2); vmcnt(4); bar}
//   counted vmcnt(4) once per tile (2 newest half-tiles in flight), never
//   drain-0 in loop; setprio around each 16-MFMA cluster; [row][64] LDS
//   with XOR-(row&7) swizzle (pre-swizzled glds16 source, HW-validated).
//   qkv 288 blk, fc 384, aproj 96, mproj split-Kx2 192 + reduce (R16).
// Attention: R11 (glds16 double-buffered K/V staging, 1 barrier/tile).

typedef unsigned short ushortT;
typedef unsigned int uintT;
typedef __attribute__((ext_vector_type(8))) __bf16 bf16x8;
typedef __attribute__((ext_vector_type(4))) float f32x4;

#define MFMA16(a, b, c) __builtin_amdgcn_mfma_f32_16x16x32_bf16(a, b, c, 0, 0, 0)

__device__ inline float b2f(ushortT u) {
  return __uint_as_float(((uintT)u) << 16);
}
__device__ inline ushortT f2b(float f) {  // round-to-nearest-even
  uintT x = __float_as_uint(f);
  uintT r = x + 0x7fffu + ((x >> 16) & 1u);
  return (ushortT)(r >> 16);
}
// pack two f32 -> two bf16 (RTZ) in one v_perm_b32
__device__ inline uintT pack_bf2(float a, float b) {
  return __builtin_amdgcn_perm(__float_as_uint(b), __float_as_uint(a),
                               0x07060302u);
}

__device__ inline float fast_exp2(float x) {
#if __has_builtin(__builtin_amdgcn_exp2f)
  return __builtin_amdgcn_exp2f(x);
#else
  return exp2f(x);
#endif
}

__device__ inline float gelu_tanh(float v) {
  float t = 0.7978845608028654f * (v + 0.044715f * v * v * v);
  return v / (1.0f + __expf(-2.0f * t));
}

// async 16B/lane global->LDS. LDS dest = wave-uniform base + lane*16.
__device__ __forceinline__ void glds16(const ushortT* g, ushortT* l) {
  __builtin_amdgcn_global_load_lds(
      (const __attribute__((address_space(1))) unsigned int*)(const void*)g,
      (__attribute__((address_space(3))) unsigned int*)(void*)l, 16, 0, 0);
}

// ------------------------------------------------------------- dtype detect
__global__ __launch_bounds__(256) void detect_dtype(
    const ushortT* __restrict__ w, int* __restrict__ flag) {
  __shared__ int red;
  if (threadIdx.x == 0) red = 0;
  __syncthreads();
  int crazy = 0;
  for (int i = threadIdx.x; i < 4096; i += 256) {
    uintT e = (w[2 * i] >> 7) & 0xFF;
    if (e >= 150) crazy = 1;
  }
  if (crazy) atomicOr(&red, 1);
  __syncthreads();
  if (threadIdx.x == 0) *flag = red;
}

// ------------------------------------------------------------- small vectors
struct VecArgs {
  const void* src[8];
  int n[8];
  int dstoff[8];
};
__global__ __launch_bounds__(256) void convert_vecs(
    VecArgs a, ushortT* __restrict__ pv, const int* __restrict__ flag) {
  int fl = *flag;
  int t = blockIdx.y;
  int i = blockIdx.x * 256 + threadIdx.x;
  if (i >= a.n[t]) return;
  float v = fl ? ((const float*)a.src[t])[i] : b2f(((const ushortT*)a.src[t])[i]);
  pv[a.dstoff[t] + i] = f2b(v);
}

// ---------------------------------------------------------------- transpose
__global__ __launch_bounds__(256) void transpose_any(
    const void* __restrict__ in, ushortT* __restrict__ out, int K, int N,
    const int* __restrict__ flag) {
  __shared__ ushortT t[32][33];
  int fl = *flag;
  int n0 = blockIdx.x * 32, k0 = blockIdx.y * 32;
  int x = threadIdx.x, y0 = threadIdx.y;
#pragma unroll
  for (int i = y0; i < 32; i += 8) {
    size_t idx = (size_t)(k0 + i) * N + n0 + x;
    t[i][x] = fl ? f2b(((const float*)in)[idx]) : ((const ushortT*)in)[idx];
  }
  __syncthreads();
#pragma unroll
  for (int i = y0; i < 32; i += 8)
    out[(size_t)(n0 + i) * K + k0 + x] = t[x][i];
}

// ------------------------------------------------------- V transpose (attn)
__global__ __launch_bounds__(256) void vtrans_kernel(
    const ushortT* __restrict__ qkv, ushortT* __restrict__ vt) {
  const int T = 2048, C3 = 2304;
  __shared__ ushortT tile[64][65];
  int bh = blockIdx.y;
  int b = bh / 12, h = bh % 12;
  int t0 = blockIdx.x * 64;
  int col = threadIdx.x & 63, rowi = threadIdx.x >> 6;
#pragma unroll
  for (int rr = rowi; rr < 64; rr += 4)
    tile[rr][col] =
        qkv[((size_t)(b * T + t0 + rr)) * C3 + 1536 + h * 64 + col];
  __syncthreads();
#pragma unroll
  for (int dd = rowi; dd < 64; dd += 4)
    vt[((size_t)bh * 64 + dd) * T + t0 + col] = tile[col][dd];
}

// ---------------------------------------------------------------- layernorm
template <int MODE>
__global__ __launch_bounds__(256) void ln_kernel(
    const void* __restrict__ xin, const ushortT* __restrict__ g,
    const ushortT* __restrict__ bb, ushortT* __restrict__ out,
    const int* __restrict__ flag) {
  const int C = 768;
  bool f32;
  if constexpr (MODE == 1) f32 = true; else f32 = (*flag != 0);
  size_t base = (size_t)blockIdx.x * C;
  int tid = threadIdx.x;
  const float* xf = (const float*)xin;
  const ushortT* xb = (const ushortT*)xin;
  float v0 = f32 ? xf[base + tid]       : b2f(xb[base + tid]);
  float v1 = f32 ? xf[base + tid + 256] : b2f(xb[base + tid + 256]);
  float v2 = f32 ? xf[base + tid + 512] : b2f(xb[base + tid + 512]);
  float s = v0 + v1 + v2;
  float q = v0 * v0 + v1 * v1 + v2 * v2;
#pragma unroll
  for (int off = 32; off; off >>= 1) {
    s += __shfl_xor(s, off);
    q += __shfl_xor(q, off);
  }
  __shared__ float as_[4], aq_[4];
  if ((tid & 63) == 0) { as_[tid >> 6] = s; aq_[tid >> 6] = q; }
  __syncthreads();
  s = as_[0] + as_[1] + as_[2] + as_[3];
  q = aq_[0] + aq_[1] + aq_[2] + aq_[3];
  float mu = s * (1.0f / 768.0f);
  float var = q * (1.0f / 768.0f) - mu * mu;
  float rs = rsqrtf(var + 1e-5f);
  ushortT* orow = out + base;
  orow[tid]       = f2b((v0 - mu) * rs * b2f(g[tid])       + b2f(bb[tid]));
  orow[tid + 256] = f2b((v1 - mu) * rs * b2f(g[tid + 256]) + b2f(bb[tid + 256]));
  orow[tid + 512] = f2b((v2 - mu) * rs * b2f(g[tid + 512]) + b2f(bb[tid + 512]));
}

// ---------------------------------------------------------------- GEMM
// C[M,N] = A[M,K] @ Bt[N,K]^T (+ bias). m201 8-phase: 256x256 tile, BK=64,
// 512 thr / 8 waves (2Mx4N -> per-wave 128x64 = acc[8][4]). 2-dbuf LDS
// (A,B each 2x32KB = 128 KiB total). 4 phases per K-tile (see header).
// Staging order: AL(t+1)@P1(t), AH(t+1)@P2(t), BL(t+2)@P3(t), BH(t+2)@P4(t)
// -> boundary vmcnt(4) guarantees tile t+1 landed with 2 half-tiles of
// t+2 still in flight. lda = row stride of A and Bt; K = per-split length;
// split sp covers [sp*K,(sp+1)*K) (grid = 8*4*nbn*nsplit).
// EPI: 0 bias->bf16 | 1 bias+gelu->bf16 | 2 bias+res(flag dtype)->fp32
//      4 partial fp32 no bias -> (sp ? res : out)
template <int EPI>
__global__ __launch_bounds__(512, 2) void gemm_m201(
    const ushortT* __restrict__ A, const ushortT* __restrict__ Bt,
    const ushortT* __restrict__ bias, const void* __restrict__ res,
    void* __restrict__ out, int N, int K, int lda, int nbn,
    const int* __restrict__ flag) {
  __shared__ ushortT As[2][256 * 64];  // 2 x 32 KiB
  __shared__ ushortT Bs[2][256 * 64];  // 2 x 32 KiB
  int fl = (EPI == 2) ? *flag : 0;
  int tid = threadIdx.x;
  int lane = tid & 63, wave = tid >> 6;
  int quad = lane >> 4, n = lane & 15, n7 = n & 7;
  int wm = (wave >> 2) * 128, wn = (wave & 3) * 64;  // 2x4 wave grid
  // XCD-locality decode + split-K (nbm = 32, strips/XCD = 4)
  int l = blockIdx.x;
  int xcd = l & 7, j = l >> 3;
  int per = 4 * nbn;
  int js = j % per, sp = j / per;
  int m0 = (xcd * 4 + js / nbn) * 256;
  int n0 = (js % nbn) * 256;
  int koff = sp * K;

  // staging: 512 thr x 16B = 8 KB = 64 rows x 128 B. thread -> row tid>>3,
  // slot tid&7; source col pre-swizzled (involution) -> LDS dest linear.
  int trow = tid >> 3;
  int tc = ((tid & 7) ^ (trow & 7)) << 3;
  const ushortT* ga = A + (size_t)(m0 + trow) * lda + koff + tc;
  const ushortT* gb = Bt + (size_t)(n0 + trow) * lda + koff + tc;

  // ds_read swizzled 16B slot: kk0 -> quad^(row&7), kk1 -> (4+quad)^(row&7);
  // fragment row = 16*i + n -> row&7 = n&7.
  const int c0 = (quad ^ n7) << 3;
  const int c1 = ((4 + quad) ^ n7) << 3;

  int kt = K >> 6;
  f32x4 acc[8][4] = {};

  // ---- prologue: tile 0 (A+B all 4 halves) + tile 1 (B both halves)
  {
    ushortT* dA0 = &As[0][0] + wave * 512;
    ushortT* dB0 = &Bs[0][0] + wave * 512;
    glds16(ga, dA0);
    glds16(ga + (size_t)64 * lda, dA0 + 4096);
    glds16(ga + (size_t)128 * lda, dA0 + 8192);
    glds16(ga + (size_t)192 * lda, dA0 + 12288);
    glds16(gb, dB0);
    glds16(gb + (size_t)64 * lda, dB0 + 4096);
    glds16(gb + (size_t)128 * lda, dB0 + 8192);
    glds16(gb + (size_t)192 * lda, dB0 + 12288);
    if (kt > 1) {
      ushortT* dB1 = &Bs[1][0] + wave * 512;
      glds16(gb + 64, dB1);
      glds16(gb + (size_t)64 * lda + 64, dB1 + 4096);
      glds16(gb + (size_t)128 * lda + 64, dB1 + 8192);
      glds16(gb + (size_t)192 * lda + 64, dB1 + 12288);
      asm volatile("s_waitcnt vmcnt(4)" ::: "memory");
    } else {
      asm volatile("s_waitcnt vmcnt(0)" ::: "memory");
    }
    __builtin_amdgcn_s_barrier();
  }

  for (int t = 0; t < kt; ++t) {
    const ushortT* ca = &As[t & 1][0];
    const ushortT* cb = &Bs[t & 1][0];
    bool pA = (t + 1) < kt;
    bool pB = (t + 2) < kt;
    ushortT* dA = &As[(t + 1) & 1][0] + wave * 512;
    ushortT* dB = &Bs[t & 1][0] + wave * 512;
    int kA = (t + 1) << 6, kB = (t + 2) << 6;

    // ---- P1: A m0-3 kk0 + B kk0; stage A-half0(t+1); MFMA acc[0..3] kk0
    bf16x8 a0[4], b0[4];
#pragma unroll
    for (int i = 0; i < 4; ++i)
      a0[i] = *(const bf16x8*)(ca + (wm + i * 16 + n) * 64 + c0);
#pragma unroll
    for (int i = 0; i < 4; ++i)
      b0[i] = *(const bf16x8*)(cb + (wn + i * 16 + n) * 64 + c0);
    if (pA) {
      glds16(ga + kA, dA);
      glds16(ga + (size_t)64 * lda + kA, dA + 4096);
    }
    __builtin_amdgcn_s_barrier();
    asm volatile("s_waitcnt lgkmcnt(0)" ::: "memory");
    __builtin_amdgcn_s_setprio(1);
#pragma unroll
    for (int mi = 0; mi < 4; ++mi)
#pragma unroll
      for (int ni = 0; ni < 4; ++ni)
        acc[mi][ni] = MFMA16(a0[mi], b0[ni], acc[mi][ni]);
    __builtin_amdgcn_s_setprio(0);
    __builtin_amdgcn_s_barrier();

    // ---- P2: A m0-3 kk1 + B kk1; stage A-half1(t+1); MFMA acc[0..3] kk1
    bf16x8 a1[4], b1[4];
#pragma unroll
    for (int i = 0; i < 4; ++i)
      a1[i] = *(const bf16x8*)(ca + (wm + i * 16 + n) * 64 + c1);
#pragma unroll
    for (int i = 0; i < 4; ++i)
      b1[i] = *(const bf16x8*)(cb + (wn + i * 16 + n) * 64 + c1);
    if (pA) {
      glds16(ga + (size_t)128 * lda + kA, dA + 8192);
      glds16(ga + (size_t)192 * lda + kA, dA + 12288);
    }
    __builtin_amdgcn_s_barrier();
    asm volatile("s_waitcnt lgkmcnt(0)" ::: "memory");
    __builtin_amdgcn_s_setprio(1);
#pragma unroll
    for (int mi = 0; mi < 4; ++mi)
#pragma unroll
      for (int ni = 0; ni < 4; ++ni)
        acc[mi][ni] = MFMA16(a1[mi], b1[ni], acc[mi][ni]);
    __builtin_amdgcn_s_setprio(0);
    __builtin_amdgcn_s_barrier();

    // ---- P3: A m4-7 kk0 (B kk0 from regs); stage B-half0(t+2)
    bf16x8 a2[4];
#pragma unroll
    for (int i = 0; i < 4; ++i)
      a2[i] = *(const bf16x8*)(ca + (wm + 64 + i * 16 + n) * 64 + c0);
    if (pB) {
      glds16(gb + kB, dB);
      glds16(gb + (size_t)64 * lda + kB, dB + 4096);
    }
    __builtin_amdgcn_s_barrier();
    asm volatile("s_waitcnt lgkmcnt(0)" ::: "memory");
    __builtin_amdgcn_s_setprio(1);
#pragma unroll
    for (int mi = 0; mi < 4; ++mi)
#pragma unroll
      for (int ni = 0; ni < 4; ++ni)
        acc[4 + mi][ni] = MFMA16(a2[mi], b0[ni], acc[4 + mi][ni]);
    __builtin_amdgcn_s_setprio(0);
    __builtin_amdgcn_s_barrier();

    // ---- P4: A m4-7 kk1; stage B-half1(t+2); boundary vmcnt(4)
    bf16x8 a3[4];
#pragma unroll
    for (int i = 0; i < 4; ++i)
      a3[i] = *(const bf16x8*)(ca + (wm + 64 + i * 16 + n) * 64 + c1);
    if (pB) {
      glds16(gb + (size_t)128 * lda + kB, dB + 8192);
      glds16(gb + (size_t)192 * lda + kB, dB + 12288);
    }
    __builtin_amdgcn_s_barrier();
    asm volatile("s_waitcnt lgkmcnt(0)" ::: "memory");
    __builtin_amdgcn_s_setprio(1);
#pragma unroll
    for (int mi = 0; mi < 4; ++mi)
#pragma unroll
      for (int ni = 0; ni < 4; ++ni)
        acc[4 + mi][ni] = MFMA16(a3[mi], b1[ni], acc[4 + mi][ni]);
    __builtin_amdgcn_s_setprio(0);
    if (pB) asm volatile("s_waitcnt vmcnt(4)" ::: "memory");
    else    asm volatile("s_waitcnt vmcnt(0)" ::: "memory");
    __builtin_amdgcn_s_barrier();
  }

  // ---- epilogue
  float* po = nullptr;
  if constexpr (EPI == 4) po = sp ? (float*)res : (float*)out;
#pragma unroll
  for (int mi = 0; mi < 8; ++mi) {
#pragma unroll
    for (int ni = 0; ni < 4; ++ni) {
      int gc = n0 + wn + ni * 16 + n;
      float bv = (EPI == 4) ? 0.0f : b2f(bias[gc]);
      int gr0 = m0 + wm + mi * 16 + quad * 4;
#pragma unroll
      for (int r = 0; r < 4; ++r) {
        size_t idx = (size_t)(gr0 + r) * N + gc;
        float v = acc[mi][ni][r] + bv;
        if constexpr (EPI == 1) {
          v = gelu_tanh(v);
          ((ushortT*)out)[idx] = f2b(v);
        } else if constexpr (EPI == 2) {
          v += fl ? ((const float*)res)[idx] : b2f(((const ushortT*)res)[idx]);
          ((float*)out)[idx] = v;
        } else if constexpr (EPI == 4) {
          po[idx] = v;
        } else {
          ((ushortT*)out)[idx] = f2b(v);
        }
      }
    }
  }
}

// ----------------------------------------------------- mproj split-K reduce
// out = P0 + P1 + bias + res(fp32); write bf16 (or fp32 if flag).
__global__ __launch_bounds__(256) void mproj_reduce(
    const float* __restrict__ P0, const float* __restrict__ P1,
    const float* __restrict__ res, const ushortT* __restrict__ bias,
    void* __restrict__ out, const int* __restrict__ flag) {
  int fl = *flag;
  size_t i0 = ((size_t)blockIdx.x * 256 + threadIdx.x) * 8;
  int col = (int)(i0 % 768);
  float o[8];
#pragma unroll
  for (int j = 0; j < 8; j += 4) {
    float4 a = *(const float4*)(P0 + i0 + j);
    float4 b = *(const float4*)(P1 + i0 + j);
    float4 r = *(const float4*)(res + i0 + j);
    o[j + 0] = a.x + b.x + r.x + b2f(bias[col + j + 0]);
    o[j + 1] = a.y + b.y + r.y + b2f(bias[col + j + 1]);
    o[j + 2] = a.z + b.z + r.z + b2f(bias[col + j + 2]);
    o[j + 3] = a.w + b.w + r.w + b2f(bias[col + j + 3]);
  }
  if (fl) {
    float* of = (float*)out;
#pragma unroll
    for (int j = 0; j < 8; ++j) of[i0 + j] = o[j];
  } else {
    uint4 pk;
    pk.x = pack_bf2(o[0], o[1]);
    pk.y = pack_bf2(o[2], o[3]);
    pk.z = pack_bf2(o[4], o[5]);
    pk.w = pack_bf2(o[6], o[7]);
    *(uint4*)((ushortT*)out + i0) = pk;
  }
}

// ---------------------------------------------------------------- attention
// Flash, causal, balanced (block pj does q-tiles pj and 31-pj = 33 k-tiles).
// 4 waves x 16 q-rows. S^T = K Q^T, O^T = V^T P^T. Fixed-offset base-2
// softmax. K/V staged via global_load_lds DMA into a double buffer with
// XOR-swizzled source cols (linear LDS dest); one __syncthreads per tile.
__global__ __launch_bounds__(256) void attn_kernel(
    const ushortT* __restrict__ qkv, const ushortT* __restrict__ vt,
    ushortT* __restrict__ y) {
  const int T = 2048, C3 = 2304;
  constexpr int LDP = 72;
  __shared__ ushortT Ks[2][64 * 64];
  __shared__ ushortT Vs[2][64 * 64];
  __shared__ ushortT Ps[4 * 16 * LDP];
  int bh = blockIdx.y;
  int b = bh / 12, h = bh % 12;
  int pj = blockIdx.x;  // 0..15
  int tid = threadIdx.x;
  int lane = tid & 63, wave = tid >> 6;
  int quad = lane >> 4, n = lane & 15, n7 = n & 7;

  const ushortT* base = qkv + (size_t)b * T * C3;
  const ushortT* kbase = base + 768 + h * 64;
  const ushortT* vbase = vt + (size_t)bh * 64 * T;
  ushortT* myP = Ps + wave * 16 * LDP;

  const float QS = 0.18033688011112042f;  // log2(e)/8
  const float MB = 20.0f;                 // fixed base-2 shift

  int qtA = pj, qtB = 31 - pj;
  int nA = qtA + 1, ntot = 33;

  int srow = lane >> 3, scol = lane & 7;
  const ushortT* kg =
      kbase + (size_t)(wave * 16 + srow) * C3 + ((scol ^ srow) << 3);
  const ushortT* vg =
      vbase + (size_t)(wave * 16 + srow) * T + ((scol ^ srow) << 3);

  const int c0 = (quad ^ n7) << 3;
  const int c1 = ((4 + quad) ^ n7) << 3;

  int qt = qtA;
  int qw = qt * 64 + wave * 16;
  bf16x8 aq[2];
  {
    const ushortT* qrow = base + (size_t)(qw + n) * C3 + h * 64 + quad * 8;
#pragma unroll
    for (int dh = 0; dh < 2; ++dh) {
      union { ushortT u[8]; bf16x8 v; } tmp;
#pragma unroll
      for (int j = 0; j < 8; ++j) tmp.u[j] = f2b(b2f(qrow[dh * 32 + j]) * QS);
      aq[dh] = tmp.v;
    }
  }
  f32x4 Ot[4] = {};
  float l_ = 0.f;

  auto stage = [&](int kt_, int buf) {
    int kof = kt_ << 6;
    ushortT* lk = &Ks[buf][0] + wave * 1024;
    ushortT* lv = &Vs[buf][0] + wave * 1024;
    glds16(kg + (size_t)kof * C3, lk);
    glds16(kg + (size_t)(kof + 8) * C3, lk + 512);
    glds16(vg + kof, lv);
    glds16(vg + (size_t)8 * T + kof, lv + 512);
  };

  stage(0, 0);
  __syncthreads();  // emits vmcnt(0): tile 0 landed

  int cur = 0;
  for (int t = 0; t < ntot; ++t) {
    int kt = (t < nA) ? t : t - nA;
    if (t + 1 < ntot) {
      int ktn = (t + 1 < nA) ? t + 1 : t + 1 - nA;
      stage(ktn, cur ^ 1);  // prefetch t+1 while computing t
    }
    const ushortT* ks = &Ks[cur][0];
    const ushortT* vs = &Vs[cur][0];

    // ---- S^T = K (Q*QS)^T  (base-2 units)
    f32x4 St[4];
#pragma unroll
    for (int g = 0; g < 4; ++g) {
      bf16x8 ka0 = *(const bf16x8*)(ks + (g * 16 + n) * 64 + c0);
      bf16x8 ka1 = *(const bf16x8*)(ks + (g * 16 + n) * 64 + c1);
      f32x4 z = {};
      z = MFMA16(ka0, aq[0], z);
      St[g] = MFMA16(ka1, aq[1], z);
    }
    // ---- diagonal-tile causal mask
    if (kt == qt) {
      int lim = wave * 16 + n;
#pragma unroll
      for (int g = 0; g < 4; ++g)
#pragma unroll
        for (int r = 0; r < 4; ++r)
          if (g * 16 + quad * 4 + r > lim) St[g][r] = -1e30f;
    }
    // ---- fixed-offset exp2, accumulate l
    float ls = 0.f;
#pragma unroll
    for (int g = 0; g < 4; ++g) {
      float p0 = fast_exp2(St[g][0] - MB);
      float p1 = fast_exp2(St[g][1] - MB);
      float p2 = fast_exp2(St[g][2] - MB);
      float p3 = fast_exp2(St[g][3] - MB);
      ls += (p0 + p1) + (p2 + p3);
      uint2 pk;
      pk.x = pack_bf2(p0, p1);
      pk.y = pack_bf2(p2, p3);
      *(uint2*)(myP + n * LDP + g * 16 + quad * 4) = pk;
    }
    ls += __shfl_xor(ls, 16);
    ls += __shfl_xor(ls, 32);
    l_ += ls;

    // ---- O^T += V^T P^T
    bf16x8 pb0 = *(const bf16x8*)(myP + n * LDP + quad * 8);
    bf16x8 pb1 = *(const bf16x8*)(myP + n * LDP + 32 + quad * 8);
#pragma unroll
    for (int dt = 0; dt < 4; ++dt) {
      bf16x8 va0 = *(const bf16x8*)(vs + (dt * 16 + n) * 64 + c0);
      bf16x8 va1 = *(const bf16x8*)(vs + (dt * 16 + n) * 64 + c1);
      Ot[dt] = MFMA16(va0, pb0, Ot[dt]);
      Ot[dt] = MFMA16(va1, pb1, Ot[dt]);
    }

    // ---- phase end: epilogue + reset for phase B
    if (kt == qt) {
      float inv = 1.0f / l_;
      int qg = qw + n;
#pragma unroll
      for (int dt = 0; dt < 4; ++dt) {
        uint2 o;
        o.x = pack_bf2(Ot[dt][0] * inv, Ot[dt][1] * inv);
        o.y = pack_bf2(Ot[dt][2] * inv, Ot[dt][3] * inv);
        *(uint2*)(y + (size_t)(b * T + qg) * 768 + h * 64 + dt * 16 +
                  quad * 4) = o;
      }
      if (t + 1 < ntot) {
        qt = qtB;
        qw = qt * 64 + wave * 16;
        const ushortT* qrow =
            base + (size_t)(qw + n) * C3 + h * 64 + quad * 8;
#pragma unroll
        for (int dh = 0; dh < 2; ++dh) {
          union { ushortT u[8]; bf16x8 v; } tmp;
#pragma unroll
          for (int j = 0; j < 8; ++j)
            tmp.u[j] = f2b(b2f(qrow[dh * 32 + j]) * QS);
          aq[dh] = tmp.v;
        }
#pragma unroll
        for (int dt = 0; dt < 4; ++dt)
#pragma unroll
          for (int r = 0; r < 4; ++r) Ot[dt][r] = 0.f;
        l_ = 0.f;
      }
    }
    __syncthreads();  // vmcnt(0): t+1 landed; all reads of buf[cur] done
    cur ^= 1;
  }
}

// ---------------------------------------------------------------- launch
extern "C" void kernel_launch(void* const* d_in, const int* in_sizes, int n_in,
                              void* d_out, int out_size, void* d_ws,
                              size_t ws_size, hipStream_t stream) {
  (void)in_sizes; (void)n_in; (void)out_size; (void)ws_size;
  const void* x       = d_in[0];
  const void* w_attn  = d_in[3];
  const void* w_aproj = d_in[5];
  const void* w_fc    = d_in[9];
  const void* w_mproj = d_in[11];

  char* ws = (char*)d_ws;
  ushortT* h1  = (ushortT*)(ws);                 // [8192,768] bf16; later vt
  ushortT* qkv = (ushortT*)(ws + 12582912);      // [8192,2304] bf16
  ushortT* yb  = (ushortT*)(ws + 50331648);      // [8192,768] bf16; later h2
  float*   x1  = (float*)(ws + 62914560);        // [8192,768] fp32
  ushortT* fcg = (ushortT*)(ws + 88080384);      // [8192,3072] bf16
  ushortT* wT0 = (ushortT*)(ws + 138412032);     // w_attn^T  [2304,768]
  ushortT* wT1 = (ushortT*)(ws + 141950976);     // w_aproj^T [768,768]
  ushortT* wT2 = (ushortT*)(ws + 143130624);     // w_fc^T    [3072,768]
  ushortT* wT3 = (ushortT*)(ws + 147849216);     // w_mproj^T [768,3072]
  ushortT* pv  = (ushortT*)(ws + 152567808);     // packed vectors (bf16)
  int*     flag = (int*)(ws + 152600576);
  ushortT* vt  = h1;   // [48][64][2048] bf16, h1 dead after qkv GEMM
  ushortT* h2  = yb;   // yb dead after aproj GEMM
  // mproj split-K partials: h1/vt + qkv regions are dead after attention.
  float*   P0  = (float*)(ws);                   // [8192,768] fp32
  float*   P1  = (float*)(ws + 25165824);        // [8192,768] fp32

  const int O_LN1G = 0, O_LN1B = 768, O_BATT = 1536, O_BAPR = 3840,
            O_LN2G = 4608, O_LN2B = 5376, O_BFC = 6144, O_BMPR = 9216;

  detect_dtype<<<1, 256, 0, stream>>>((const ushortT*)w_fc, flag);

  VecArgs va;
  va.src[0] = d_in[1];  va.n[0] = 768;  va.dstoff[0] = O_LN1G;
  va.src[1] = d_in[2];  va.n[1] = 768;  va.dstoff[1] = O_LN1B;
  va.src[2] = d_in[4];  va.n[2] = 2304; va.dstoff[2] = O_BATT;
  va.src[3] = d_in[6];  va.n[3] = 768;  va.dstoff[3] = O_BAPR;
  va.src[4] = d_in[7];  va.n[4] = 768;  va.dstoff[4] = O_LN2G;
  va.src[5] = d_in[8];  va.n[5] = 768;  va.dstoff[5] = O_LN2B;
  va.src[6] = d_in[10]; va.n[6] = 3072; va.dstoff[6] = O_BFC;
  va.src[7] = d_in[12]; va.n[7] = 768;  va.dstoff[7] = O_BMPR;
  convert_vecs<<<dim3(12, 8), 256, 0, stream>>>(va, pv, flag);

  dim3 tb(32, 8);
  transpose_any<<<dim3(72, 24), tb, 0, stream>>>(w_attn, wT0, 768, 2304, flag);
  transpose_any<<<dim3(24, 24), tb, 0, stream>>>(w_aproj, wT1, 768, 768, flag);
  transpose_any<<<dim3(96, 24), tb, 0, stream>>>(w_fc, wT2, 768, 3072, flag);
  transpose_any<<<dim3(24, 96), tb, 0, stream>>>(w_mproj, wT3, 3072, 768, flag);

  ln_kernel<0><<<8192, 256, 0, stream>>>(x, pv + O_LN1G, pv + O_LN1B, h1, flag);
  // qkv: 256x256, nbn=9 -> 288 blocks
  gemm_m201<0><<<288, 512, 0, stream>>>(
      h1, wT0, pv + O_BATT, nullptr, qkv, 2304, 768, 768, 9, flag);
  vtrans_kernel<<<dim3(32, 48), 256, 0, stream>>>(qkv, vt);
  attn_kernel<<<dim3(16, 48), 256, 0, stream>>>(qkv, vt, yb);
  // aproj: nbn=3 -> 96 blocks
  gemm_m201<2><<<96, 512, 0, stream>>>(
      yb, wT1, pv + O_BAPR, x, x1, 768, 768, 768, 3, flag);
  ln_kernel<1><<<8192, 256, 0, stream>>>(x1, pv + O_LN2G, pv + O_LN2B, h2, flag);
  // fc: nbn=12 -> 384 blocks
  gemm_m201<1><<<384, 512, 0, stream>>>(
      h2, wT2, pv + O_BFC, nullptr, fcg, 3072, 768, 768, 12, flag);
  // mproj: split-K x2 (K=1536 each, lda=3072), nbn=3 -> 192 blocks;
  // sp=0 -> P0, sp=1 -> P1; reduce adds bias + residual x1.
  gemm_m201<4><<<192, 512, 0, stream>>>(
      fcg, wT3, nullptr, P1, P0, 768, 1536, 3072, 3, flag);
  mproj_reduce<<<3072, 256, 0, stream>>>(
      P0, P1, x1, pv + O_BMPR, d_out, flag);
}

// Round 9
// 409.071 us; speedup vs baseline: 1.1027x; 1.1027x over previous
//
#include <hip/hip_runtime.h>

// GPT-2 block forward, MI355X/gfx950. B=4 T=2048 C=768 H=12 D=64; M=8192.
// R18: launch-chain consolidation. Six GEMM structures all measured
// ~550 TF @ K=768 (shape roofline, m102 curve) -> stop restructuring GEMM.
//   - ONE prep kernel replaces detect_dtype + convert_vecs + 4x
//     transpose_any (6951 blocks; per-block LOCAL dtype detect via 64
//     exponent samples of w_fc -> no cross-kernel flag dependency;
//     block 0 still writes *flag for downstream ln/gemm epilogues).
//   - GEMMs: R14/R16 gemm_8p (best measured, 419 us), mproj plain EPI=3
//     (no split-K, no reduce launch); fl bug fixed (EPI>=2 reads flag).
//   - Launches: 15 -> 9.
// Attention: R11 (glds16 double-buffered K/V staging, 1 barrier/tile).

typedef unsigned short ushortT;
typedef unsigned int uintT;
typedef __attribute__((ext_vector_type(8))) __bf16 bf16x8;
typedef __attribute__((ext_vector_type(4))) float f32x4;

#define MFMA16(a, b, c) __builtin_amdgcn_mfma_f32_16x16x32_bf16(a, b, c, 0, 0, 0)

__device__ inline float b2f(ushortT u) {
  return __uint_as_float(((uintT)u) << 16);
}
__device__ inline ushortT f2b(float f) {  // round-to-nearest-even
  uintT x = __float_as_uint(f);
  uintT r = x + 0x7fffu + ((x >> 16) & 1u);
  return (ushortT)(r >> 16);
}
// pack two f32 -> two bf16 (RTZ) in one v_perm_b32
__device__ inline uintT pack_bf2(float a, float b) {
  return __builtin_amdgcn_perm(__float_as_uint(b), __float_as_uint(a),
                               0x07060302u);
}

__device__ inline float fast_exp2(float x) {
#if __has_builtin(__builtin_amdgcn_exp2f)
  return __builtin_amdgcn_exp2f(x);
#else
  return exp2f(x);
#endif
}

__device__ inline float gelu_tanh(float v) {
  float t = 0.7978845608028654f * (v + 0.044715f * v * v * v);
  return v / (1.0f + __expf(-2.0f * t));
}

// async 16B/lane global->LDS. LDS dest = wave-uniform base + lane*16.
__device__ __forceinline__ void glds16(const ushortT* g, ushortT* l) {
  __builtin_amdgcn_global_load_lds(
      (const __attribute__((address_space(1))) unsigned int*)(const void*)g,
      (__attribute__((address_space(3))) unsigned int*)(void*)l, 16, 0, 0);
}

// ------------------------------------------------------------- prep (fused)
// One kernel: 4 weight transposes + 8 vector converts + flag write.
// Per-block LOCAL dtype detect: sample 64 even-index bf16-view exponents of
// w_fc (fp32 data: P(all 64 < 150) ~ 4e-15; bf16 weights never >= 150 since
// that means |x| >= 2^23). Matches detect_dtype's population (w[2i], i<4096).
struct VecArgs {
  const void* src[8];
  int n[8];
  int dstoff[8];
};

__global__ __launch_bounds__(256) void prep_kernel(
    const void* __restrict__ w_attn, const void* __restrict__ w_aproj,
    const void* __restrict__ w_fc, const void* __restrict__ w_mproj,
    VecArgs va, ushortT* __restrict__ wT0, ushortT* __restrict__ wT1,
    ushortT* __restrict__ wT2, ushortT* __restrict__ wT3,
    ushortT* __restrict__ pv, int* __restrict__ flag) {
  __shared__ int sfl;
  __shared__ ushortT tile[32][33];
  int tid = threadIdx.x;
  {
    int crazy = 0;
    if (tid < 64) {
      uintT e = (((const ushortT*)w_fc)[2 * (tid * 64)] >> 7) & 0xFF;
      crazy = (e >= 150) ? 1 : 0;
    }
    unsigned long long m = __ballot(crazy != 0);
    if (tid == 0) sfl = (m != 0ull) ? 1 : 0;
    __syncthreads();
  }
  int fl = sfl;
  int b = (int)blockIdx.x;
  if (b == 0 && tid == 0) *flag = fl;

  // region table: transposes are (in[K x N] -> out[N x K]) in 32x32 tiles,
  // gx = N/32 tiles along N.
  const int T0 = 1728;            // w_attn  K=768  N=2304 (72x24)
  const int T1 = T0 + 576;        // w_aproj K=768  N=768  (24x24)
  const int T2 = T1 + 2304;       // w_fc    K=768  N=3072 (96x24)
  const int T3 = T2 + 2304;       // w_mproj K=3072 N=768  (24x96)

  const void* in = nullptr;
  ushortT* out = nullptr;
  int K = 0, N = 0, gx = 0, t = 0;
  if (b < T0)      { in = w_attn;  out = wT0; K = 768;  N = 2304; gx = 72; t = b; }
  else if (b < T1) { in = w_aproj; out = wT1; K = 768;  N = 768;  gx = 24; t = b - T0; }
  else if (b < T2) { in = w_fc;    out = wT2; K = 768;  N = 3072; gx = 96; t = b - T1; }
  else if (b < T3) { in = w_mproj; out = wT3; K = 3072; N = 768;  gx = 24; t = b - T2; }
  else {
    // vector converts: chunks of 256 elems across the 8 vectors
    int c = b - T3;
    int v = 0;
    for (;;) {
      int nch = (va.n[v] + 255) >> 8;
      if (c < nch) break;
      c -= nch; ++v;
    }
    int i = c * 256 + tid;
    if (i < va.n[v]) {
      float x = fl ? ((const float*)va.src[v])[i]
                   : b2f(((const ushortT*)va.src[v])[i]);
      pv[va.dstoff[v] + i] = f2b(x);
    }
    return;
  }

  int n0 = (t % gx) * 32, k0 = (t / gx) * 32;
  int x = tid & 31, y0 = tid >> 5;
#pragma unroll
  for (int i = y0; i < 32; i += 8) {
    size_t idx = (size_t)(k0 + i) * N + n0 + x;
    tile[i][x] = fl ? f2b(((const float*)in)[idx]) : ((const ushortT*)in)[idx];
  }
  __syncthreads();
#pragma unroll
  for (int i = y0; i < 32; i += 8)
    out[(size_t)(n0 + i) * K + k0 + x] = tile[x][i];
}

// ------------------------------------------------------- V transpose (attn)
__global__ __launch_bounds__(256) void vtrans_kernel(
    const ushortT* __restrict__ qkv, ushortT* __restrict__ vt) {
  const int T = 2048, C3 = 2304;
  __shared__ ushortT tile[64][65];
  int bh = blockIdx.y;
  int b = bh / 12, h = bh % 12;
  int t0 = blockIdx.x * 64;
  int col = threadIdx.x & 63, rowi = threadIdx.x >> 6;
#pragma unroll
  for (int rr = rowi; rr < 64; rr += 4)
    tile[rr][col] =
        qkv[((size_t)(b * T + t0 + rr)) * C3 + 1536 + h * 64 + col];
  __syncthreads();
#pragma unroll
  for (int dd = rowi; dd < 64; dd += 4)
    vt[((size_t)bh * 64 + dd) * T + t0 + col] = tile[col][dd];
}

// ---------------------------------------------------------------- layernorm
template <int MODE>
__global__ __launch_bounds__(256) void ln_kernel(
    const void* __restrict__ xin, const ushortT* __restrict__ g,
    const ushortT* __restrict__ bb, ushortT* __restrict__ out,
    const int* __restrict__ flag) {
  const int C = 768;
  bool f32;
  if constexpr (MODE == 1) f32 = true; else f32 = (*flag != 0);
  size_t base = (size_t)blockIdx.x * C;
  int tid = threadIdx.x;
  const float* xf = (const float*)xin;
  const ushortT* xb = (const ushortT*)xin;
  float v0 = f32 ? xf[base + tid]       : b2f(xb[base + tid]);
  float v1 = f32 ? xf[base + tid + 256] : b2f(xb[base + tid + 256]);
  float v2 = f32 ? xf[base + tid + 512] : b2f(xb[base + tid + 512]);
  float s = v0 + v1 + v2;
  float q = v0 * v0 + v1 * v1 + v2 * v2;
#pragma unroll
  for (int off = 32; off; off >>= 1) {
    s += __shfl_xor(s, off);
    q += __shfl_xor(q, off);
  }
  __shared__ float as_[4], aq_[4];
  if ((tid & 63) == 0) { as_[tid >> 6] = s; aq_[tid >> 6] = q; }
  __syncthreads();
  s = as_[0] + as_[1] + as_[2] + as_[3];
  q = aq_[0] + aq_[1] + aq_[2] + aq_[3];
  float mu = s * (1.0f / 768.0f);
  float var = q * (1.0f / 768.0f) - mu * mu;
  float rs = rsqrtf(var + 1e-5f);
  ushortT* orow = out + base;
  orow[tid]       = f2b((v0 - mu) * rs * b2f(g[tid])       + b2f(bb[tid]));
  orow[tid + 256] = f2b((v1 - mu) * rs * b2f(g[tid + 256]) + b2f(bb[tid + 256]));
  orow[tid + 512] = f2b((v2 - mu) * rs * b2f(g[tid + 512]) + b2f(bb[tid + 512]));
}

// ---------------------------------------------------------------- GEMM
// C[M,N] = A[M,K] @ Bt[N,K]^T + bias. BM=128, BK=32, 256 thr (4 waves).
// BN=256: wave grid 1x4 (per-wave 128x64, MI=8,NI=4), 2 phases/K-tile.
// BN=128: wave grid 2x2 (per-wave 64x64,  MI=4,NI=4), 1 phase/K-tile.
// 3-slot LDS ring; stage tile t+2 during t; counted end-of-tile vmcnt.
// lda = row stride of A and Bt (elements); split sp covers [sp*K,(sp+1)*K).
// EPI: 0 bias->bf16 | 1 bias+gelu->bf16 | 2 bias+res(flag dtype)->fp32
//      3 bias+res(fp32)->flag-dtype out | 4 partial fp32 (no bias)
template <int EPI, int BN>
__global__ __launch_bounds__(256, 2) void gemm_8p(
    const ushortT* __restrict__ A, const ushortT* __restrict__ Bt,
    const ushortT* __restrict__ bias, const void* __restrict__ res,
    void* __restrict__ out, int N, int K, int lda, int nbm, int nbn,
    const int* __restrict__ flag) {
  constexpr int MI = (BN == 256) ? 8 : 4;
  constexpr int NI = 4;
  __shared__ ushortT As3[3][128 * 32];
  __shared__ ushortT Bs3[3][BN * 32];
  int fl = (EPI >= 2) ? *flag : 0;
  int tid = threadIdx.x;
  int lane = tid & 63, wave = tid >> 6;
  int quad = lane >> 4, n = lane & 15;
  int wm, wn;
  if constexpr (BN == 256) { wm = 0; wn = wave * 64; }
  else { wm = (wave >> 1) * 64; wn = (wave & 1) * 64; }
  // XCD-locality decode + split-K
  int l = blockIdx.x;
  int xcd = l & 7, j = l >> 3;
  int per = (nbm >> 3) * nbn;
  int js = j % per, sp = j / per;
  int m0 = (xcd * (nbm >> 3) + js / nbn) * 128;
  int n0 = (js % nbn) * BN;
  int koff = sp * K;

  int trow = tid >> 2;
  int tc = (((tid & 3) ^ ((trow >> 1) & 3)) << 3);
  const ushortT* ga = A + (size_t)(m0 + trow) * lda + koff + tc;
  const ushortT* gb = Bt + (size_t)(n0 + trow) * lda + koff + tc;

  const int cs = (quad ^ ((n >> 1) & 3)) << 3;

  int kt = K >> 5;
  f32x4 acc[MI][NI] = {};

  auto stage = [&](int tt, int slot) {
    int k0 = tt << 5;
    ushortT* la = &As3[slot][0] + wave * 512;
    ushortT* lb = &Bs3[slot][0] + wave * 512;
    glds16(ga + k0, la);
    glds16(ga + (size_t)64 * lda + k0, la + 2048);
    glds16(gb + k0, lb);
    glds16(gb + (size_t)64 * lda + k0, lb + 2048);
    if constexpr (BN == 256) {
      glds16(gb + (size_t)128 * lda + k0, lb + 4096);
      glds16(gb + (size_t)192 * lda + k0, lb + 6144);
    }
  };

  stage(0, 0);
  stage(1, 1);
  if constexpr (BN == 256)
    asm volatile("s_waitcnt vmcnt(6)" ::: "memory");
  else
    asm volatile("s_waitcnt vmcnt(4)" ::: "memory");
  __builtin_amdgcn_s_barrier();

  int cur = 0;
  for (int t = 0; t < kt; ++t) {
    const ushortT* ca = &As3[cur][0];
    const ushortT* cb = &Bs3[cur][0];
    int nxt = cur + 2; if (nxt >= 3) nxt -= 3;
    bool pf = (t + 2) < kt;
    int pk0 = (t + 2) << 5;
    ushortT* la = &As3[nxt][0] + wave * 512;
    ushortT* lb = &Bs3[nxt][0] + wave * 512;

    bf16x8 af[4], bfr[NI];
#pragma unroll
    for (int i = 0; i < 4; ++i)
      af[i] = *(const bf16x8*)(ca + (wm + i * 16 + n) * 32 + cs);
#pragma unroll
    for (int i = 0; i < NI; ++i)
      bfr[i] = *(const bf16x8*)(cb + (wn + i * 16 + n) * 32 + cs);
    if (pf) {
      glds16(ga + pk0, la);
      glds16(ga + (size_t)64 * lda + pk0, la + 2048);
      glds16(gb + pk0, lb);
      if constexpr (BN == 128)
        glds16(gb + (size_t)64 * lda + pk0, lb + 2048);
    }
    __builtin_amdgcn_s_barrier();
    __builtin_amdgcn_s_setprio(1);
#pragma unroll
    for (int mi = 0; mi < 4; ++mi)
#pragma unroll
      for (int ni = 0; ni < NI; ++ni)
        acc[mi][ni] = MFMA16(af[mi], bfr[ni], acc[mi][ni]);
    __builtin_amdgcn_s_setprio(0);
    if constexpr (BN == 256) {
      __builtin_amdgcn_s_barrier();
#pragma unroll
      for (int i = 0; i < 4; ++i)
        af[i] = *(const bf16x8*)(ca + (64 + i * 16 + n) * 32 + cs);
      if (pf) {
        glds16(gb + (size_t)64 * lda + pk0, lb + 2048);
        glds16(gb + (size_t)128 * lda + pk0, lb + 4096);
        glds16(gb + (size_t)192 * lda + pk0, lb + 6144);
      }
      __builtin_amdgcn_s_barrier();
      __builtin_amdgcn_s_setprio(1);
#pragma unroll
      for (int mi = 0; mi < 4; ++mi)
#pragma unroll
        for (int ni = 0; ni < NI; ++ni)
          acc[4 + mi][ni] = MFMA16(af[mi], bfr[ni], acc[4 + mi][ni]);
      __builtin_amdgcn_s_setprio(0);
    }
    if (pf) {
      if constexpr (BN == 256)
        asm volatile("s_waitcnt vmcnt(6)" ::: "memory");
      else
        asm volatile("s_waitcnt vmcnt(4)" ::: "memory");
    } else {
      asm volatile("s_waitcnt vmcnt(0)" ::: "memory");
    }
    __builtin_amdgcn_s_barrier();

    cur = cur + 1; if (cur == 3) cur = 0;
  }

  // ---- epilogue
  float* po = nullptr;
  if constexpr (EPI == 4) po = sp ? (float*)res : (float*)out;
#pragma unroll
  for (int mi = 0; mi < MI; ++mi) {
#pragma unroll
    for (int ni = 0; ni < NI; ++ni) {
      int gc = n0 + wn + ni * 16 + n;
      float bv = (EPI == 4) ? 0.0f : b2f(bias[gc]);
      int gr0 = m0 + wm + mi * 16 + quad * 4;
#pragma unroll
      for (int r = 0; r < 4; ++r) {
        size_t idx = (size_t)(gr0 + r) * N + gc;
        float v = acc[mi][ni][r] + bv;
        if constexpr (EPI == 1) {
          v = gelu_tanh(v);
          ((ushortT*)out)[idx] = f2b(v);
        } else if constexpr (EPI == 2) {
          v += fl ? ((const float*)res)[idx] : b2f(((const ushortT*)res)[idx]);
          ((float*)out)[idx] = v;
        } else if constexpr (EPI == 3) {
          v += ((const float*)res)[idx];
          if (fl) ((float*)out)[idx] = v;
          else    ((ushortT*)out)[idx] = f2b(v);
        } else if constexpr (EPI == 4) {
          po[idx] = v;
        } else {
          ((ushortT*)out)[idx] = f2b(v);
        }
      }
    }
  }
}

// ---------------------------------------------------------------- attention
// Flash, causal, balanced (block pj does q-tiles pj and 31-pj = 33 k-tiles).
// 4 waves x 16 q-rows. S^T = K Q^T, O^T = V^T P^T. Fixed-offset base-2
// softmax. K/V staged via global_load_lds DMA into a double buffer with
// XOR-swizzled source cols (linear LDS dest); one __syncthreads per tile.
__global__ __launch_bounds__(256) void attn_kernel(
    const ushortT* __restrict__ qkv, const ushortT* __restrict__ vt,
    ushortT* __restrict__ y) {
  const int T = 2048, C3 = 2304;
  constexpr int LDP = 72;
  __shared__ ushortT Ks[2][64 * 64];
  __shared__ ushortT Vs[2][64 * 64];
  __shared__ ushortT Ps[4 * 16 * LDP];
  int bh = blockIdx.y;
  int b = bh / 12, h = bh % 12;
  int pj = blockIdx.x;  // 0..15
  int tid = threadIdx.x;
  int lane = tid & 63, wave = tid >> 6;
  int quad = lane >> 4, n = lane & 15, n7 = n & 7;

  const ushortT* base = qkv + (size_t)b * T * C3;
  const ushortT* kbase = base + 768 + h * 64;
  const ushortT* vbase = vt + (size_t)bh * 64 * T;
  ushortT* myP = Ps + wave * 16 * LDP;

  const float QS = 0.18033688011112042f;  // log2(e)/8
  const float MB = 20.0f;                 // fixed base-2 shift

  int qtA = pj, qtB = 31 - pj;
  int nA = qtA + 1, ntot = 33;

  int srow = lane >> 3, scol = lane & 7;
  const ushortT* kg =
      kbase + (size_t)(wave * 16 + srow) * C3 + ((scol ^ srow) << 3);
  const ushortT* vg =
      vbase + (size_t)(wave * 16 + srow) * T + ((scol ^ srow) << 3);

  const int c0 = (quad ^ n7) << 3;
  const int c1 = ((4 + quad) ^ n7) << 3;

  int qt = qtA;
  int qw = qt * 64 + wave * 16;
  bf16x8 aq[2];
  {
    const ushortT* qrow = base + (size_t)(qw + n) * C3 + h * 64 + quad * 8;
#pragma unroll
    for (int dh = 0; dh < 2; ++dh) {
      union { ushortT u[8]; bf16x8 v; } tmp;
#pragma unroll
      for (int j = 0; j < 8; ++j) tmp.u[j] = f2b(b2f(qrow[dh * 32 + j]) * QS);
      aq[dh] = tmp.v;
    }
  }
  f32x4 Ot[4] = {};
  float l_ = 0.f;

  auto stage = [&](int kt_, int buf) {
    int kof = kt_ << 6;
    ushortT* lk = &Ks[buf][0] + wave * 1024;
    ushortT* lv = &Vs[buf][0] + wave * 1024;
    glds16(kg + (size_t)kof * C3, lk);
    glds16(kg + (size_t)(kof + 8) * C3, lk + 512);
    glds16(vg + kof, lv);
    glds16(vg + (size_t)8 * T + kof, lv + 512);
  };

  stage(0, 0);
  __syncthreads();  // emits vmcnt(0): tile 0 landed

  int cur = 0;
  for (int t = 0; t < ntot; ++t) {
    int kt = (t < nA) ? t : t - nA;
    if (t + 1 < ntot) {
      int ktn = (t + 1 < nA) ? t + 1 : t + 1 - nA;
      stage(ktn, cur ^ 1);  // prefetch t+1 while computing t
    }
    const ushortT* ks = &Ks[cur][0];
    const ushortT* vs = &Vs[cur][0];

    // ---- S^T = K (Q*QS)^T  (base-2 units)
    f32x4 St[4];
#pragma unroll
    for (int g = 0; g < 4; ++g) {
      bf16x8 ka0 = *(const bf16x8*)(ks + (g * 16 + n) * 64 + c0);
      bf16x8 ka1 = *(const bf16x8*)(ks + (g * 16 + n) * 64 + c1);
      f32x4 z = {};
      z = MFMA16(ka0, aq[0], z);
      St[g] = MFMA16(ka1, aq[1], z);
    }
    // ---- diagonal-tile causal mask
    if (kt == qt) {
      int lim = wave * 16 + n;
#pragma unroll
      for (int g = 0; g < 4; ++g)
#pragma unroll
        for (int r = 0; r < 4; ++r)
          if (g * 16 + quad * 4 + r > lim) St[g][r] = -1e30f;
    }
    // ---- fixed-offset exp2, accumulate l
    float ls = 0.f;
#pragma unroll
    for (int g = 0; g < 4; ++g) {
      float p0 = fast_exp2(St[g][0] - MB);
      float p1 = fast_exp2(St[g][1] - MB);
      float p2 = fast_exp2(St[g][2] - MB);
      float p3 = fast_exp2(St[g][3] - MB);
      ls += (p0 + p1) + (p2 + p3);
      uint2 pk;
      pk.x = pack_bf2(p0, p1);
      pk.y = pack_bf2(p2, p3);
      *(uint2*)(myP + n * LDP + g * 16 + quad * 4) = pk;
    }
    ls += __shfl_xor(ls, 16);
    ls += __shfl_xor(ls, 32);
    l_ += ls;

    // ---- O^T += V^T P^T
    bf16x8 pb0 = *(const bf16x8*)(myP + n * LDP + quad * 8);
    bf16x8 pb1 = *(const bf16x8*)(myP + n * LDP + 32 + quad * 8);
#pragma unroll
    for (int dt = 0; dt < 4; ++dt) {
      bf16x8 va0 = *(const bf16x8*)(vs + (dt * 16 + n) * 64 + c0);
      bf16x8 va1 = *(const bf16x8*)(vs + (dt * 16 + n) * 64 + c1);
      Ot[dt] = MFMA16(va0, pb0, Ot[dt]);
      Ot[dt] = MFMA16(va1, pb1, Ot[dt]);
    }

    // ---- phase end: epilogue + reset for phase B
    if (kt == qt) {
      float inv = 1.0f / l_;
      int qg = qw + n;
#pragma unroll
      for (int dt = 0; dt < 4; ++dt) {
        uint2 o;
        o.x = pack_bf2(Ot[dt][0] * inv, Ot[dt][1] * inv);
        o.y = pack_bf2(Ot[dt][2] * inv, Ot[dt][3] * inv);
        *(uint2*)(y + (size_t)(b * T + qg) * 768 + h * 64 + dt * 16 +
                  quad * 4) = o;
      }
      if (t + 1 < ntot) {
        qt = qtB;
        qw = qt * 64 + wave * 16;
        const ushortT* qrow =
            base + (size_t)(qw + n) * C3 + h * 64 + quad * 8;
#pragma unroll
        for (int dh = 0; dh < 2; ++dh) {
          union { ushortT u[8]; bf16x8 v; } tmp;
#pragma unroll
          for (int j = 0; j < 8; ++j)
            tmp.u[j] = f2b(b2f(qrow[dh * 32 + j]) * QS);
          aq[dh] = tmp.v;
        }
#pragma unroll
        for (int dt = 0; dt < 4; ++dt)
#pragma unroll
          for (int r = 0; r < 4; ++r) Ot[dt][r] = 0.f;
        l_ = 0.f;
      }
    }
    __syncthreads();  // vmcnt(0): t+1 landed; all reads of buf[cur] done
    cur ^= 1;
  }
}

// ---------------------------------------------------------------- launch
extern "C" void kernel_launch(void* const* d_in, const int* in_sizes, int n_in,
                              void* d_out, int out_size, void* d_ws,
                              size_t ws_size, hipStream_t stream) {
  (void)in_sizes; (void)n_in; (void)out_size; (void)ws_size;
  const void* x       = d_in[0];
  const void* w_attn  = d_in[3];
  const void* w_aproj = d_in[5];
  const void* w_fc    = d_in[9];
  const void* w_mproj = d_in[11];

  char* ws = (char*)d_ws;
  ushortT* h1  = (ushortT*)(ws);                 // [8192,768] bf16; later vt
  ushortT* qkv = (ushortT*)(ws + 12582912);      // [8192,2304] bf16
  ushortT* yb  = (ushortT*)(ws + 50331648);      // [8192,768] bf16; later h2
  float*   x1  = (float*)(ws + 62914560);        // [8192,768] fp32
  ushortT* fcg = (ushortT*)(ws + 88080384);      // [8192,3072] bf16
  ushortT* wT0 = (ushortT*)(ws + 138412032);     // w_attn^T  [2304,768]
  ushortT* wT1 = (ushortT*)(ws + 141950976);     // w_aproj^T [768,768]
  ushortT* wT2 = (ushortT*)(ws + 143130624);     // w_fc^T    [3072,768]
  ushortT* wT3 = (ushortT*)(ws + 147849216);     // w_mproj^T [768,3072]
  ushortT* pv  = (ushortT*)(ws + 152567808);     // packed vectors (bf16)
  int*     flag = (int*)(ws + 152600576);
  ushortT* vt  = h1;   // [48][64][2048] bf16, h1 dead after qkv GEMM
  ushortT* h2  = yb;   // yb dead after aproj GEMM

  const int O_LN1G = 0, O_LN1B = 768, O_BATT = 1536, O_BAPR = 3840,
            O_LN2G = 4608, O_LN2B = 5376, O_BFC = 6144, O_BMPR = 9216;

  VecArgs va;
  va.src[0] = d_in[1];  va.n[0] = 768;  va.dstoff[0] = O_LN1G;
  va.src[1] = d_in[2];  va.n[1] = 768;  va.dstoff[1] = O_LN1B;
  va.src[2] = d_in[4];  va.n[2] = 2304; va.dstoff[2] = O_BATT;
  va.src[3] = d_in[6];  va.n[3] = 768;  va.dstoff[3] = O_BAPR;
  va.src[4] = d_in[7];  va.n[4] = 768;  va.dstoff[4] = O_LN2G;
  va.src[5] = d_in[8];  va.n[5] = 768;  va.dstoff[5] = O_LN2B;
  va.src[6] = d_in[10]; va.n[6] = 3072; va.dstoff[6] = O_BFC;
  va.src[7] = d_in[12]; va.n[7] = 768;  va.dstoff[7] = O_BMPR;

  // fused prep: 4 transposes (1728+576+2304+2304) + 39 convert chunks
  prep_kernel<<<6951, 256, 0, stream>>>(
      w_attn, w_aproj, w_fc, w_mproj, va, wT0, wT1, wT2, wT3, pv, flag);

  ln_kernel<0><<<8192, 256, 0, stream>>>(x, pv + O_LN1G, pv + O_LN1B, h1, flag);
  // qkv: nbm=64, BN=256 -> nbn=9 -> 576 blocks
  gemm_8p<0, 256><<<576, 256, 0, stream>>>(
      h1, wT0, pv + O_BATT, nullptr, qkv, 2304, 768, 768, 64, 9, flag);
  vtrans_kernel<<<dim3(32, 48), 256, 0, stream>>>(qkv, vt);
  attn_kernel<<<dim3(16, 48), 256, 0, stream>>>(qkv, vt, yb);
  // aproj: nbm=64, BN=128 -> nbn=6 -> 384 blocks
  gemm_8p<2, 128><<<384, 256, 0, stream>>>(
      yb, wT1, pv + O_BAPR, x, x1, 768, 768, 768, 64, 6, flag);
  ln_kernel<1><<<8192, 256, 0, stream>>>(x1, pv + O_LN2G, pv + O_LN2B, h2, flag);
  // fc: nbm=64, BN=256 -> nbn=12 -> 768 blocks
  gemm_8p<1, 256><<<768, 256, 0, stream>>>(
      h2, wT2, pv + O_BFC, nullptr, fcg, 3072, 768, 768, 64, 12, flag);
  // mproj: nbm=64, BN=128 -> nbn=6 -> 384 blocks, K=3072 (EPI=3: +res x1)
  gemm_8p<3, 128><<<384, 256, 0, stream>>>(
      fcg, wT3, pv + O_BMPR, x1, d_out, 768, 3072, 3072, 64, 6, flag);
}

// Round 10
// 401.962 us; speedup vs baseline: 1.1222x; 1.0177x over previous
//
#include <hip/hip_runtime.h>

// GPT-2 block forward, MI355X/gfx950. B=4 T=2048 C=768 H=12 D=64; M=8192.
// R19 = R18 (best: 409 us) + two more serial-chain removals:
//   - vtrans fused into qkv epilogue (EPI=5): V columns (gc>=1536) are
//     written ONLY to vt, transposed (attn never reads V from qkv layout).
//     vt relocated to the fcg region (dead until fc; h1 is qkv's live A).
//   - ln1 merged into prep as 8192 extra blocks (raw gamma/beta reads with
//     local dtype detect).
//   Launches: 9 -> 7.
// GEMMs: R14/R16 gemm_8p (measured shape-roofline ~550 TF @ K=768).
// Attention: R11 (glds16 double-buffered K/V staging, 1 barrier/tile).

typedef unsigned short ushortT;
typedef unsigned int uintT;
typedef __attribute__((ext_vector_type(8))) __bf16 bf16x8;
typedef __attribute__((ext_vector_type(4))) float f32x4;

#define MFMA16(a, b, c) __builtin_amdgcn_mfma_f32_16x16x32_bf16(a, b, c, 0, 0, 0)

__device__ inline float b2f(ushortT u) {
  return __uint_as_float(((uintT)u) << 16);
}
__device__ inline ushortT f2b(float f) {  // round-to-nearest-even
  uintT x = __float_as_uint(f);
  uintT r = x + 0x7fffu + ((x >> 16) & 1u);
  return (ushortT)(r >> 16);
}
// pack two f32 -> two bf16 (RTZ) in one v_perm_b32
__device__ inline uintT pack_bf2(float a, float b) {
  return __builtin_amdgcn_perm(__float_as_uint(b), __float_as_uint(a),
                               0x07060302u);
}

__device__ inline float fast_exp2(float x) {
#if __has_builtin(__builtin_amdgcn_exp2f)
  return __builtin_amdgcn_exp2f(x);
#else
  return exp2f(x);
#endif
}

__device__ inline float gelu_tanh(float v) {
  float t = 0.7978845608028654f * (v + 0.044715f * v * v * v);
  return v / (1.0f + __expf(-2.0f * t));
}

// async 16B/lane global->LDS. LDS dest = wave-uniform base + lane*16.
__device__ __forceinline__ void glds16(const ushortT* g, ushortT* l) {
  __builtin_amdgcn_global_load_lds(
      (const __attribute__((address_space(1))) unsigned int*)(const void*)g,
      (__attribute__((address_space(3))) unsigned int*)(void*)l, 16, 0, 0);
}

// ------------------------------------------------------------- prep (fused)
// One kernel: 4 weight transposes + 8 vector converts + flag + LN1.
// Per-block LOCAL dtype detect: sample 64 even-index bf16-view exponents of
// w_fc (fp32 data: P(all 64 < 150) ~ 4e-15; bf16 weights never >= 150).
struct VecArgs {
  const void* src[8];
  int n[8];
  int dstoff[8];
};

__global__ __launch_bounds__(256) void prep_kernel(
    const void* __restrict__ w_attn, const void* __restrict__ w_aproj,
    const void* __restrict__ w_fc, const void* __restrict__ w_mproj,
    VecArgs va, ushortT* __restrict__ wT0, ushortT* __restrict__ wT1,
    ushortT* __restrict__ wT2, ushortT* __restrict__ wT3,
    ushortT* __restrict__ pv, int* __restrict__ flag,
    const void* __restrict__ x, const void* __restrict__ ln1g,
    const void* __restrict__ ln1b, ushortT* __restrict__ h1) {
  __shared__ int sfl;
  __shared__ ushortT tile[32][33];
  __shared__ float as_[4], aq_[4];
  int tid = threadIdx.x;
  {
    int crazy = 0;
    if (tid < 64) {
      uintT e = (((const ushortT*)w_fc)[2 * (tid * 64)] >> 7) & 0xFF;
      crazy = (e >= 150) ? 1 : 0;
    }
    unsigned long long m = __ballot(crazy != 0);
    if (tid == 0) sfl = (m != 0ull) ? 1 : 0;
    __syncthreads();
  }
  int fl = sfl;
  int b = (int)blockIdx.x;
  if (b == 0 && tid == 0) *flag = fl;

  const int T0 = 1728;            // w_attn  K=768  N=2304 (72x24)
  const int T1 = T0 + 576;        // w_aproj K=768  N=768  (24x24)
  const int T2 = T1 + 2304;       // w_fc    K=768  N=3072 (96x24)
  const int T3 = T2 + 2304;       // w_mproj K=3072 N=768  (24x96)  = 6912
  const int T4 = T3 + 39;         // vector converts (39 chunks)

  if (b >= T4) {
    // ---- LN1: row = b - T4 of x[8192][768] -> h1 (bf16)
    int row = b - T4;
    size_t base = (size_t)row * 768;
    const float* xf = (const float*)x;
    const ushortT* xb = (const ushortT*)x;
    float v0 = fl ? xf[base + tid]       : b2f(xb[base + tid]);
    float v1 = fl ? xf[base + tid + 256] : b2f(xb[base + tid + 256]);
    float v2 = fl ? xf[base + tid + 512] : b2f(xb[base + tid + 512]);
    float s = v0 + v1 + v2;
    float q = v0 * v0 + v1 * v1 + v2 * v2;
#pragma unroll
    for (int off = 32; off; off >>= 1) {
      s += __shfl_xor(s, off);
      q += __shfl_xor(q, off);
    }
    if ((tid & 63) == 0) { as_[tid >> 6] = s; aq_[tid >> 6] = q; }
    __syncthreads();
    s = as_[0] + as_[1] + as_[2] + as_[3];
    q = aq_[0] + aq_[1] + aq_[2] + aq_[3];
    float mu = s * (1.0f / 768.0f);
    float var = q * (1.0f / 768.0f) - mu * mu;
    float rs = rsqrtf(var + 1e-5f);
    const float* gf = (const float*)ln1g;
    const ushortT* gb_ = (const ushortT*)ln1g;
    const float* bf = (const float*)ln1b;
    const ushortT* bb_ = (const ushortT*)ln1b;
    ushortT* orow = h1 + base;
#pragma unroll
    for (int jj = 0; jj < 3; ++jj) {
      int c = tid + jj * 256;
      float gv = fl ? gf[c] : b2f(gb_[c]);
      float bv = fl ? bf[c] : b2f(bb_[c]);
      float vv = (jj == 0) ? v0 : (jj == 1) ? v1 : v2;
      orow[c] = f2b((vv - mu) * rs * gv + bv);
    }
    return;
  }

  const void* in = nullptr;
  ushortT* out = nullptr;
  int K = 0, N = 0, gx = 0, t = 0;
  if (b < T0)      { in = w_attn;  out = wT0; K = 768;  N = 2304; gx = 72; t = b; }
  else if (b < T1) { in = w_aproj; out = wT1; K = 768;  N = 768;  gx = 24; t = b - T0; }
  else if (b < T2) { in = w_fc;    out = wT2; K = 768;  N = 3072; gx = 96; t = b - T1; }
  else if (b < T3) { in = w_mproj; out = wT3; K = 3072; N = 768;  gx = 24; t = b - T2; }
  else {
    // vector converts: chunks of 256 elems across the 8 vectors
    int c = b - T3;
    int v = 0;
    for (;;) {
      int nch = (va.n[v] + 255) >> 8;
      if (c < nch) break;
      c -= nch; ++v;
    }
    int i = c * 256 + tid;
    if (i < va.n[v]) {
      float xx = fl ? ((const float*)va.src[v])[i]
                    : b2f(((const ushortT*)va.src[v])[i]);
      pv[va.dstoff[v] + i] = f2b(xx);
    }
    return;
  }

  int n0 = (t % gx) * 32, k0 = (t / gx) * 32;
  int xx = tid & 31, y0 = tid >> 5;
#pragma unroll
  for (int i = y0; i < 32; i += 8) {
    size_t idx = (size_t)(k0 + i) * N + n0 + xx;
    tile[i][xx] = fl ? f2b(((const float*)in)[idx]) : ((const ushortT*)in)[idx];
  }
  __syncthreads();
#pragma unroll
  for (int i = y0; i < 32; i += 8)
    out[(size_t)(n0 + i) * K + k0 + xx] = tile[xx][i];
}

// ---------------------------------------------------------------- layernorm
template <int MODE>
__global__ __launch_bounds__(256) void ln_kernel(
    const void* __restrict__ xin, const ushortT* __restrict__ g,
    const ushortT* __restrict__ bb, ushortT* __restrict__ out,
    const int* __restrict__ flag) {
  const int C = 768;
  bool f32;
  if constexpr (MODE == 1) f32 = true; else f32 = (*flag != 0);
  size_t base = (size_t)blockIdx.x * C;
  int tid = threadIdx.x;
  const float* xf = (const float*)xin;
  const ushortT* xb = (const ushortT*)xin;
  float v0 = f32 ? xf[base + tid]       : b2f(xb[base + tid]);
  float v1 = f32 ? xf[base + tid + 256] : b2f(xb[base + tid + 256]);
  float v2 = f32 ? xf[base + tid + 512] : b2f(xb[base + tid + 512]);
  float s = v0 + v1 + v2;
  float q = v0 * v0 + v1 * v1 + v2 * v2;
#pragma unroll
  for (int off = 32; off; off >>= 1) {
    s += __shfl_xor(s, off);
    q += __shfl_xor(q, off);
  }
  __shared__ float as_[4], aq_[4];
  if ((tid & 63) == 0) { as_[tid >> 6] = s; aq_[tid >> 6] = q; }
  __syncthreads();
  s = as_[0] + as_[1] + as_[2] + as_[3];
  q = aq_[0] + aq_[1] + aq_[2] + aq_[3];
  float mu = s * (1.0f / 768.0f);
  float var = q * (1.0f / 768.0f) - mu * mu;
  float rs = rsqrtf(var + 1e-5f);
  ushortT* orow = out + base;
  orow[tid]       = f2b((v0 - mu) * rs * b2f(g[tid])       + b2f(bb[tid]));
  orow[tid + 256] = f2b((v1 - mu) * rs * b2f(g[tid + 256]) + b2f(bb[tid + 256]));
  orow[tid + 512] = f2b((v2 - mu) * rs * b2f(g[tid + 512]) + b2f(bb[tid + 512]));
}

// ---------------------------------------------------------------- GEMM
// C[M,N] = A[M,K] @ Bt[N,K]^T + bias. BM=128, BK=32, 256 thr (4 waves).
// BN=256: wave grid 1x4 (per-wave 128x64, MI=8,NI=4), 2 phases/K-tile.
// BN=128: wave grid 2x2 (per-wave 64x64,  MI=4,NI=4), 1 phase/K-tile.
// 3-slot LDS ring; stage tile t+2 during t; counted end-of-tile vmcnt.
// EPI: 0 bias->bf16 | 1 bias+gelu->bf16 | 2 bias+res(flag dtype)->fp32
//      3 bias+res(fp32)->flag-dtype out | 5 qkv: Q/K->out, V->res
//      (transposed vt[(b*12+h)*64+d][t], 8B RNE packs)
template <int EPI, int BN>
__global__ __launch_bounds__(256, 2) void gemm_8p(
    const ushortT* __restrict__ A, const ushortT* __restrict__ Bt,
    const ushortT* __restrict__ bias, const void* __restrict__ res,
    void* __restrict__ out, int N, int K, int lda, int nbm, int nbn,
    const int* __restrict__ flag) {
  constexpr int MI = (BN == 256) ? 8 : 4;
  constexpr int NI = 4;
  __shared__ ushortT As3[3][128 * 32];
  __shared__ ushortT Bs3[3][BN * 32];
  int fl = (EPI == 2 || EPI == 3) ? *flag : 0;
  int tid = threadIdx.x;
  int lane = tid & 63, wave = tid >> 6;
  int quad = lane >> 4, n = lane & 15;
  int wm, wn;
  if constexpr (BN == 256) { wm = 0; wn = wave * 64; }
  else { wm = (wave >> 1) * 64; wn = (wave & 1) * 64; }
  // XCD-locality decode
  int l = blockIdx.x;
  int xcd = l & 7, j = l >> 3;
  int m0 = (xcd * (nbm >> 3) + j / nbn) * 128;
  int n0 = (j % nbn) * BN;

  int trow = tid >> 2;
  int tc = (((tid & 3) ^ ((trow >> 1) & 3)) << 3);
  const ushortT* ga = A + (size_t)(m0 + trow) * lda + tc;
  const ushortT* gb = Bt + (size_t)(n0 + trow) * lda + tc;

  const int cs = (quad ^ ((n >> 1) & 3)) << 3;

  int kt = K >> 5;
  f32x4 acc[MI][NI] = {};

  auto stage = [&](int tt, int slot) {
    int k0 = tt << 5;
    ushortT* la = &As3[slot][0] + wave * 512;
    ushortT* lb = &Bs3[slot][0] + wave * 512;
    glds16(ga + k0, la);
    glds16(ga + (size_t)64 * lda + k0, la + 2048);
    glds16(gb + k0, lb);
    glds16(gb + (size_t)64 * lda + k0, lb + 2048);
    if constexpr (BN == 256) {
      glds16(gb + (size_t)128 * lda + k0, lb + 4096);
      glds16(gb + (size_t)192 * lda + k0, lb + 6144);
    }
  };

  stage(0, 0);
  stage(1, 1);
  if constexpr (BN == 256)
    asm volatile("s_waitcnt vmcnt(6)" ::: "memory");
  else
    asm volatile("s_waitcnt vmcnt(4)" ::: "memory");
  __builtin_amdgcn_s_barrier();

  int cur = 0;
  for (int t = 0; t < kt; ++t) {
    const ushortT* ca = &As3[cur][0];
    const ushortT* cb = &Bs3[cur][0];
    int nxt = cur + 2; if (nxt >= 3) nxt -= 3;
    bool pf = (t + 2) < kt;
    int pk0 = (t + 2) << 5;
    ushortT* la = &As3[nxt][0] + wave * 512;
    ushortT* lb = &Bs3[nxt][0] + wave * 512;

    bf16x8 af[4], bfr[NI];
#pragma unroll
    for (int i = 0; i < 4; ++i)
      af[i] = *(const bf16x8*)(ca + (wm + i * 16 + n) * 32 + cs);
#pragma unroll
    for (int i = 0; i < NI; ++i)
      bfr[i] = *(const bf16x8*)(cb + (wn + i * 16 + n) * 32 + cs);
    if (pf) {
      glds16(ga + pk0, la);
      glds16(ga + (size_t)64 * lda + pk0, la + 2048);
      glds16(gb + pk0, lb);
      if constexpr (BN == 128)
        glds16(gb + (size_t)64 * lda + pk0, lb + 2048);
    }
    __builtin_amdgcn_s_barrier();
    __builtin_amdgcn_s_setprio(1);
#pragma unroll
    for (int mi = 0; mi < 4; ++mi)
#pragma unroll
      for (int ni = 0; ni < NI; ++ni)
        acc[mi][ni] = MFMA16(af[mi], bfr[ni], acc[mi][ni]);
    __builtin_amdgcn_s_setprio(0);
    if constexpr (BN == 256) {
      __builtin_amdgcn_s_barrier();
#pragma unroll
      for (int i = 0; i < 4; ++i)
        af[i] = *(const bf16x8*)(ca + (64 + i * 16 + n) * 32 + cs);
      if (pf) {
        glds16(gb + (size_t)64 * lda + pk0, lb + 2048);
        glds16(gb + (size_t)128 * lda + pk0, lb + 4096);
        glds16(gb + (size_t)192 * lda + pk0, lb + 6144);
      }
      __builtin_amdgcn_s_barrier();
      __builtin_amdgcn_s_setprio(1);
#pragma unroll
      for (int mi = 0; mi < 4; ++mi)
#pragma unroll
        for (int ni = 0; ni < NI; ++ni)
          acc[4 + mi][ni] = MFMA16(af[mi], bfr[ni], acc[4 + mi][ni]);
      __builtin_amdgcn_s_setprio(0);
    }
    if (pf) {
      if constexpr (BN == 256)
        asm volatile("s_waitcnt vmcnt(6)" ::: "memory");
      else
        asm volatile("s_waitcnt vmcnt(4)" ::: "memory");
    } else {
      asm volatile("s_waitcnt vmcnt(0)" ::: "memory");
    }
    __builtin_amdgcn_s_barrier();

    cur = cur + 1; if (cur == 3) cur = 0;
  }

  // ---- epilogue
#pragma unroll
  for (int mi = 0; mi < MI; ++mi) {
#pragma unroll
    for (int ni = 0; ni < NI; ++ni) {
      int gc = n0 + wn + ni * 16 + n;
      float bv = b2f(bias[gc]);
      int gr0 = m0 + wm + mi * 16 + quad * 4;
      if constexpr (EPI == 5) {
        float v0 = acc[mi][ni][0] + bv;
        float v1 = acc[mi][ni][1] + bv;
        float v2 = acc[mi][ni][2] + bv;
        float v3 = acc[mi][ni][3] + bv;
        if (gc < 1536) {
          ushortT* o = (ushortT*)out;
          o[(size_t)(gr0 + 0) * N + gc] = f2b(v0);
          o[(size_t)(gr0 + 1) * N + gc] = f2b(v1);
          o[(size_t)(gr0 + 2) * N + gc] = f2b(v2);
          o[(size_t)(gr0 + 3) * N + gc] = f2b(v3);
        } else {
          int hh = (gc - 1536) >> 6, dd = (gc - 1536) & 63;
          int bb = gr0 >> 11, tin = gr0 & 2047;
          ushortT* vp = (ushortT*)res;
          uint2 o;
          o.x = (uintT)f2b(v0) | ((uintT)f2b(v1) << 16);
          o.y = (uintT)f2b(v2) | ((uintT)f2b(v3) << 16);
          *(uint2*)(vp + ((size_t)(bb * 12 + hh) * 64 + dd) * 2048 + tin) = o;
        }
      } else {
#pragma unroll
        for (int r = 0; r < 4; ++r) {
          size_t idx = (size_t)(gr0 + r) * N + gc;
          float v = acc[mi][ni][r] + bv;
          if constexpr (EPI == 1) {
            v = gelu_tanh(v);
            ((ushortT*)out)[idx] = f2b(v);
          } else if constexpr (EPI == 2) {
            v += fl ? ((const float*)res)[idx] : b2f(((const ushortT*)res)[idx]);
            ((float*)out)[idx] = v;
          } else if constexpr (EPI == 3) {
            v += ((const float*)res)[idx];
            if (fl) ((float*)out)[idx] = v;
            else    ((ushortT*)out)[idx] = f2b(v);
          } else {
            ((ushortT*)out)[idx] = f2b(v);
          }
        }
      }
    }
  }
}

// ---------------------------------------------------------------- attention
// Flash, causal, balanced (block pj does q-tiles pj and 31-pj = 33 k-tiles).
// 4 waves x 16 q-rows. S^T = K Q^T, O^T = V^T P^T. Fixed-offset base-2
// softmax. K/V staged via global_load_lds DMA into a double buffer with
// XOR-swizzled source cols (linear LDS dest); one __syncthreads per tile.
__global__ __launch_bounds__(256) void attn_kernel(
    const ushortT* __restrict__ qkv, const ushortT* __restrict__ vt,
    ushortT* __restrict__ y) {
  const int T = 2048, C3 = 2304;
  constexpr int LDP = 72;
  __shared__ ushortT Ks[2][64 * 64];
  __shared__ ushortT Vs[2][64 * 64];
  __shared__ ushortT Ps[4 * 16 * LDP];
  int bh = blockIdx.y;
  int b = bh / 12, h = bh % 12;
  int pj = blockIdx.x;  // 0..15
  int tid = threadIdx.x;
  int lane = tid & 63, wave = tid >> 6;
  int quad = lane >> 4, n = lane & 15, n7 = n & 7;

  const ushortT* base = qkv + (size_t)b * T * C3;
  const ushortT* kbase = base + 768 + h * 64;
  const ushortT* vbase = vt + (size_t)bh * 64 * T;
  ushortT* myP = Ps + wave * 16 * LDP;

  const float QS = 0.18033688011112042f;  // log2(e)/8
  const float MB = 20.0f;                 // fixed base-2 shift

  int qtA = pj, qtB = 31 - pj;
  int nA = qtA + 1, ntot = 33;

  int srow = lane >> 3, scol = lane & 7;
  const ushortT* kg =
      kbase + (size_t)(wave * 16 + srow) * C3 + ((scol ^ srow) << 3);
  const ushortT* vg =
      vbase + (size_t)(wave * 16 + srow) * T + ((scol ^ srow) << 3);

  const int c0 = (quad ^ n7) << 3;
  const int c1 = ((4 + quad) ^ n7) << 3;

  int qt = qtA;
  int qw = qt * 64 + wave * 16;
  bf16x8 aq[2];
  {
    const ushortT* qrow = base + (size_t)(qw + n) * C3 + h * 64 + quad * 8;
#pragma unroll
    for (int dh = 0; dh < 2; ++dh) {
      union { ushortT u[8]; bf16x8 v; } tmp;
#pragma unroll
      for (int j = 0; j < 8; ++j) tmp.u[j] = f2b(b2f(qrow[dh * 32 + j]) * QS);
      aq[dh] = tmp.v;
    }
  }
  f32x4 Ot[4] = {};
  float l_ = 0.f;

  auto stage = [&](int kt_, int buf) {
    int kof = kt_ << 6;
    ushortT* lk = &Ks[buf][0] + wave * 1024;
    ushortT* lv = &Vs[buf][0] + wave * 1024;
    glds16(kg + (size_t)kof * C3, lk);
    glds16(kg + (size_t)(kof + 8) * C3, lk + 512);
    glds16(vg + kof, lv);
    glds16(vg + (size_t)8 * T + kof, lv + 512);
  };

  stage(0, 0);
  __syncthreads();  // emits vmcnt(0): tile 0 landed

  int cur = 0;
  for (int t = 0; t < ntot; ++t) {
    int kt = (t < nA) ? t : t - nA;
    if (t + 1 < ntot) {
      int ktn = (t + 1 < nA) ? t + 1 : t + 1 - nA;
      stage(ktn, cur ^ 1);  // prefetch t+1 while computing t
    }
    const ushortT* ks = &Ks[cur][0];
    const ushortT* vs = &Vs[cur][0];

    // ---- S^T = K (Q*QS)^T  (base-2 units)
    f32x4 St[4];
#pragma unroll
    for (int g = 0; g < 4; ++g) {
      bf16x8 ka0 = *(const bf16x8*)(ks + (g * 16 + n) * 64 + c0);
      bf16x8 ka1 = *(const bf16x8*)(ks + (g * 16 + n) * 64 + c1);
      f32x4 z = {};
      z = MFMA16(ka0, aq[0], z);
      St[g] = MFMA16(ka1, aq[1], z);
    }
    // ---- diagonal-tile causal mask
    if (kt == qt) {
      int lim = wave * 16 + n;
#pragma unroll
      for (int g = 0; g < 4; ++g)
#pragma unroll
        for (int r = 0; r < 4; ++r)
          if (g * 16 + quad * 4 + r > lim) St[g][r] = -1e30f;
    }
    // ---- fixed-offset exp2, accumulate l
    float ls = 0.f;
#pragma unroll
    for (int g = 0; g < 4; ++g) {
      float p0 = fast_exp2(St[g][0] - MB);
      float p1 = fast_exp2(St[g][1] - MB);
      float p2 = fast_exp2(St[g][2] - MB);
      float p3 = fast_exp2(St[g][3] - MB);
      ls += (p0 + p1) + (p2 + p3);
      uint2 pk;
      pk.x = pack_bf2(p0, p1);
      pk.y = pack_bf2(p2, p3);
      *(uint2*)(myP + n * LDP + g * 16 + quad * 4) = pk;
    }
    ls += __shfl_xor(ls, 16);
    ls += __shfl_xor(ls, 32);
    l_ += ls;

    // ---- O^T += V^T P^T
    bf16x8 pb0 = *(const bf16x8*)(myP + n * LDP + quad * 8);
    bf16x8 pb1 = *(const bf16x8*)(myP + n * LDP + 32 + quad * 8);
#pragma unroll
    for (int dt = 0; dt < 4; ++dt) {
      bf16x8 va0 = *(const bf16x8*)(vs + (dt * 16 + n) * 64 + c0);
      bf16x8 va1 = *(const bf16x8*)(vs + (dt * 16 + n) * 64 + c1);
      Ot[dt] = MFMA16(va0, pb0, Ot[dt]);
      Ot[dt] = MFMA16(va1, pb1, Ot[dt]);
    }

    // ---- phase end: epilogue + reset for phase B
    if (kt == qt) {
      float inv = 1.0f / l_;
      int qg = qw + n;
#pragma unroll
      for (int dt = 0; dt < 4; ++dt) {
        uint2 o;
        o.x = pack_bf2(Ot[dt][0] * inv, Ot[dt][1] * inv);
        o.y = pack_bf2(Ot[dt][2] * inv, Ot[dt][3] * inv);
        *(uint2*)(y + (size_t)(b * T + qg) * 768 + h * 64 + dt * 16 +
                  quad * 4) = o;
      }
      if (t + 1 < ntot) {
        qt = qtB;
        qw = qt * 64 + wave * 16;
        const ushortT* qrow =
            base + (size_t)(qw + n) * C3 + h * 64 + quad * 8;
#pragma unroll
        for (int dh = 0; dh < 2; ++dh) {
          union { ushortT u[8]; bf16x8 v; } tmp;
#pragma unroll
          for (int j = 0; j < 8; ++j)
            tmp.u[j] = f2b(b2f(qrow[dh * 32 + j]) * QS);
          aq[dh] = tmp.v;
        }
#pragma unroll
        for (int dt = 0; dt < 4; ++dt)
#pragma unroll
          for (int r = 0; r < 4; ++r) Ot[dt][r] = 0.f;
        l_ = 0.f;
      }
    }
    __syncthreads();  // vmcnt(0): t+1 landed; all reads of buf[cur] done
    cur ^= 1;
  }
}

// ---------------------------------------------------------------- launch
extern "C" void kernel_launch(void* const* d_in, const int* in_sizes, int n_in,
                              void* d_out, int out_size, void* d_ws,
                              size_t ws_size, hipStream_t stream) {
  (void)in_sizes; (void)n_in; (void)out_size; (void)ws_size;
  const void* x       = d_in[0];
  const void* w_attn  = d_in[3];
  const void* w_aproj = d_in[5];
  const void* w_fc    = d_in[9];
  const void* w_mproj = d_in[11];

  char* ws = (char*)d_ws;
  ushortT* h1  = (ushortT*)(ws);                 // [8192,768] bf16 (ln1 out)
  ushortT* qkv = (ushortT*)(ws + 12582912);      // [8192,2304] bf16
  ushortT* yb  = (ushortT*)(ws + 50331648);      // [8192,768] bf16; later h2
  float*   x1  = (float*)(ws + 62914560);        // [8192,768] fp32
  ushortT* fcg = (ushortT*)(ws + 88080384);      // [8192,3072] bf16
  ushortT* wT0 = (ushortT*)(ws + 138412032);     // w_attn^T  [2304,768]
  ushortT* wT1 = (ushortT*)(ws + 141950976);     // w_aproj^T [768,768]
  ushortT* wT2 = (ushortT*)(ws + 143130624);     // w_fc^T    [3072,768]
  ushortT* wT3 = (ushortT*)(ws + 147849216);     // w_mproj^T [768,3072]
  ushortT* pv  = (ushortT*)(ws + 152567808);     // packed vectors (bf16)
  int*     flag = (int*)(ws + 152600576);
  // vt: [48][64][2048] bf16 = 12.58 MB, lives in the fcg region (dead until
  // fc, which runs after attention). NOT h1 (live A-input of qkv GEMM).
  ushortT* vt  = fcg;
  ushortT* h2  = yb;   // yb dead after aproj GEMM

  const int O_LN1G = 0, O_LN1B = 768, O_BATT = 1536, O_BAPR = 3840,
            O_LN2G = 4608, O_LN2B = 5376, O_BFC = 6144, O_BMPR = 9216;

  VecArgs va;
  va.src[0] = d_in[1];  va.n[0] = 768;  va.dstoff[0] = O_LN1G;
  va.src[1] = d_in[2];  va.n[1] = 768;  va.dstoff[1] = O_LN1B;
  va.src[2] = d_in[4];  va.n[2] = 2304; va.dstoff[2] = O_BATT;
  va.src[3] = d_in[6];  va.n[3] = 768;  va.dstoff[3] = O_BAPR;
  va.src[4] = d_in[7];  va.n[4] = 768;  va.dstoff[4] = O_LN2G;
  va.src[5] = d_in[8];  va.n[5] = 768;  va.dstoff[5] = O_LN2B;
  va.src[6] = d_in[10]; va.n[6] = 3072; va.dstoff[6] = O_BFC;
  va.src[7] = d_in[12]; va.n[7] = 768;  va.dstoff[7] = O_BMPR;

  // fused prep: 4 transposes (6912) + 39 convert chunks + 8192 LN1 rows
  prep_kernel<<<15143, 256, 0, stream>>>(
      w_attn, w_aproj, w_fc, w_mproj, va, wT0, wT1, wT2, wT3, pv, flag,
      x, d_in[1], d_in[2], h1);

  // qkv (EPI=5): Q/K -> qkv, V -> vt transposed. 576 blocks.
  gemm_8p<5, 256><<<576, 256, 0, stream>>>(
      h1, wT0, pv + O_BATT, vt, qkv, 2304, 768, 768, 64, 9, flag);
  attn_kernel<<<dim3(16, 48), 256, 0, stream>>>(qkv, vt, yb);
  // aproj: 384 blocks
  gemm_8p<2, 128><<<384, 256, 0, stream>>>(
      yb, wT1, pv + O_BAPR, x, x1, 768, 768, 768, 64, 6, flag);
  ln_kernel<1><<<8192, 256, 0, stream>>>(x1, pv + O_LN2G, pv + O_LN2B, h2, flag);
  // fc: 768 blocks (fcg overwrites vt region — attn already done)
  gemm_8p<1, 256><<<768, 256, 0, stream>>>(
      h2, wT2, pv + O_BFC, nullptr, fcg, 3072, 768, 768, 64, 12, flag);
  // mproj: 384 blocks, K=3072 (EPI=3: +res x1 -> d_out)
  gemm_8p<3, 128><<<384, 256, 0, stream>>>(
      fcg, wT3, pv + O_BMPR, x1, d_out, 768, 3072, 3072, 64, 6, flag);
}

// Round 11
// 400.463 us; speedup vs baseline: 1.1264x; 1.0037x over previous
//
#include <hip/hip_runtime.h>

// GPT-2 block forward, MI355X/gfx950. B=4 T=2048 C=768 H=12 D=64; M=8192.
// R20 = R19 (best: 402 us) + attention shared-staging:
//   block pj stages each k-tile ONCE (t=0..31-pj) and applies it to BOTH
//   q-tiles (qtB=31-pj always; qtA=pj while t<=pj), K/V fragments reused
//   in-register for both MFMA sets. Stages/barriers/LDS-reads -26%;
//   MFMA & softmax totals unchanged. Both outputs written at the end.
// GEMMs: R14/R16 gemm_8p (measured shape-roofline ~550 TF); qkv EPI=5
// writes V transposed to vt (vtrans fused); prep fuses transposes+
// converts+LN1; 7 launches.

typedef unsigned short ushortT;
typedef unsigned int uintT;
typedef __attribute__((ext_vector_type(8))) __bf16 bf16x8;
typedef __attribute__((ext_vector_type(4))) float f32x4;

#define MFMA16(a, b, c) __builtin_amdgcn_mfma_f32_16x16x32_bf16(a, b, c, 0, 0, 0)

__device__ inline float b2f(ushortT u) {
  return __uint_as_float(((uintT)u) << 16);
}
__device__ inline ushortT f2b(float f) {  // round-to-nearest-even
  uintT x = __float_as_uint(f);
  uintT r = x + 0x7fffu + ((x >> 16) & 1u);
  return (ushortT)(r >> 16);
}
// pack two f32 -> two bf16 (RTZ) in one v_perm_b32
__device__ inline uintT pack_bf2(float a, float b) {
  return __builtin_amdgcn_perm(__float_as_uint(b), __float_as_uint(a),
                               0x07060302u);
}

__device__ inline float fast_exp2(float x) {
#if __has_builtin(__builtin_amdgcn_exp2f)
  return __builtin_amdgcn_exp2f(x);
#else
  return exp2f(x);
#endif
}

__device__ inline float gelu_tanh(float v) {
  float t = 0.7978845608028654f * (v + 0.044715f * v * v * v);
  return v / (1.0f + __expf(-2.0f * t));
}

// async 16B/lane global->LDS. LDS dest = wave-uniform base + lane*16.
__device__ __forceinline__ void glds16(const ushortT* g, ushortT* l) {
  __builtin_amdgcn_global_load_lds(
      (const __attribute__((address_space(1))) unsigned int*)(const void*)g,
      (__attribute__((address_space(3))) unsigned int*)(void*)l, 16, 0, 0);
}

// ------------------------------------------------------------- prep (fused)
// One kernel: 4 weight transposes + 8 vector converts + flag + LN1.
// Per-block LOCAL dtype detect: sample 64 even-index bf16-view exponents of
// w_fc (fp32 data: P(all 64 < 150) ~ 4e-15; bf16 weights never >= 150).
struct VecArgs {
  const void* src[8];
  int n[8];
  int dstoff[8];
};

__global__ __launch_bounds__(256) void prep_kernel(
    const void* __restrict__ w_attn, const void* __restrict__ w_aproj,
    const void* __restrict__ w_fc, const void* __restrict__ w_mproj,
    VecArgs va, ushortT* __restrict__ wT0, ushortT* __restrict__ wT1,
    ushortT* __restrict__ wT2, ushortT* __restrict__ wT3,
    ushortT* __restrict__ pv, int* __restrict__ flag,
    const void* __restrict__ x, const void* __restrict__ ln1g,
    const void* __restrict__ ln1b, ushortT* __restrict__ h1) {
  __shared__ int sfl;
  __shared__ ushortT tile[32][33];
  __shared__ float as_[4], aq_[4];
  int tid = threadIdx.x;
  {
    int crazy = 0;
    if (tid < 64) {
      uintT e = (((const ushortT*)w_fc)[2 * (tid * 64)] >> 7) & 0xFF;
      crazy = (e >= 150) ? 1 : 0;
    }
    unsigned long long m = __ballot(crazy != 0);
    if (tid == 0) sfl = (m != 0ull) ? 1 : 0;
    __syncthreads();
  }
  int fl = sfl;
  int b = (int)blockIdx.x;
  if (b == 0 && tid == 0) *flag = fl;

  const int T0 = 1728;            // w_attn  K=768  N=2304 (72x24)
  const int T1 = T0 + 576;        // w_aproj K=768  N=768  (24x24)
  const int T2 = T1 + 2304;       // w_fc    K=768  N=3072 (96x24)
  const int T3 = T2 + 2304;       // w_mproj K=3072 N=768  (24x96)  = 6912
  const int T4 = T3 + 39;         // vector converts (39 chunks)

  if (b >= T4) {
    // ---- LN1: row = b - T4 of x[8192][768] -> h1 (bf16)
    int row = b - T4;
    size_t base = (size_t)row * 768;
    const float* xf = (const float*)x;
    const ushortT* xb = (const ushortT*)x;
    float v0 = fl ? xf[base + tid]       : b2f(xb[base + tid]);
    float v1 = fl ? xf[base + tid + 256] : b2f(xb[base + tid + 256]);
    float v2 = fl ? xf[base + tid + 512] : b2f(xb[base + tid + 512]);
    float s = v0 + v1 + v2;
    float q = v0 * v0 + v1 * v1 + v2 * v2;
#pragma unroll
    for (int off = 32; off; off >>= 1) {
      s += __shfl_xor(s, off);
      q += __shfl_xor(q, off);
    }
    if ((tid & 63) == 0) { as_[tid >> 6] = s; aq_[tid >> 6] = q; }
    __syncthreads();
    s = as_[0] + as_[1] + as_[2] + as_[3];
    q = aq_[0] + aq_[1] + aq_[2] + aq_[3];
    float mu = s * (1.0f / 768.0f);
    float var = q * (1.0f / 768.0f) - mu * mu;
    float rs = rsqrtf(var + 1e-5f);
    const float* gf = (const float*)ln1g;
    const ushortT* gb_ = (const ushortT*)ln1g;
    const float* bf = (const float*)ln1b;
    const ushortT* bb_ = (const ushortT*)ln1b;
    ushortT* orow = h1 + base;
#pragma unroll
    for (int jj = 0; jj < 3; ++jj) {
      int c = tid + jj * 256;
      float gv = fl ? gf[c] : b2f(gb_[c]);
      float bv = fl ? bf[c] : b2f(bb_[c]);
      float vv = (jj == 0) ? v0 : (jj == 1) ? v1 : v2;
      orow[c] = f2b((vv - mu) * rs * gv + bv);
    }
    return;
  }

  const void* in = nullptr;
  ushortT* out = nullptr;
  int K = 0, N = 0, gx = 0, t = 0;
  if (b < T0)      { in = w_attn;  out = wT0; K = 768;  N = 2304; gx = 72; t = b; }
  else if (b < T1) { in = w_aproj; out = wT1; K = 768;  N = 768;  gx = 24; t = b - T0; }
  else if (b < T2) { in = w_fc;    out = wT2; K = 768;  N = 3072; gx = 96; t = b - T1; }
  else if (b < T3) { in = w_mproj; out = wT3; K = 3072; N = 768;  gx = 24; t = b - T2; }
  else {
    // vector converts: chunks of 256 elems across the 8 vectors
    int c = b - T3;
    int v = 0;
    for (;;) {
      int nch = (va.n[v] + 255) >> 8;
      if (c < nch) break;
      c -= nch; ++v;
    }
    int i = c * 256 + tid;
    if (i < va.n[v]) {
      float xx = fl ? ((const float*)va.src[v])[i]
                    : b2f(((const ushortT*)va.src[v])[i]);
      pv[va.dstoff[v] + i] = f2b(xx);
    }
    return;
  }

  int n0 = (t % gx) * 32, k0 = (t / gx) * 32;
  int xx = tid & 31, y0 = tid >> 5;
#pragma unroll
  for (int i = y0; i < 32; i += 8) {
    size_t idx = (size_t)(k0 + i) * N + n0 + xx;
    tile[i][xx] = fl ? f2b(((const float*)in)[idx]) : ((const ushortT*)in)[idx];
  }
  __syncthreads();
#pragma unroll
  for (int i = y0; i < 32; i += 8)
    out[(size_t)(n0 + i) * K + k0 + xx] = tile[xx][i];
}

// ---------------------------------------------------------------- layernorm
template <int MODE>
__global__ __launch_bounds__(256) void ln_kernel(
    const void* __restrict__ xin, const ushortT* __restrict__ g,
    const ushortT* __restrict__ bb, ushortT* __restrict__ out,
    const int* __restrict__ flag) {
  const int C = 768;
  bool f32;
  if constexpr (MODE == 1) f32 = true; else f32 = (*flag != 0);
  size_t base = (size_t)blockIdx.x * C;
  int tid = threadIdx.x;
  const float* xf = (const float*)xin;
  const ushortT* xb = (const ushortT*)xin;
  float v0 = f32 ? xf[base + tid]       : b2f(xb[base + tid]);
  float v1 = f32 ? xf[base + tid + 256] : b2f(xb[base + tid + 256]);
  float v2 = f32 ? xf[base + tid + 512] : b2f(xb[base + tid + 512]);
  float s = v0 + v1 + v2;
  float q = v0 * v0 + v1 * v1 + v2 * v2;
#pragma unroll
  for (int off = 32; off; off >>= 1) {
    s += __shfl_xor(s, off);
    q += __shfl_xor(q, off);
  }
  __shared__ float as_[4], aq_[4];
  if ((tid & 63) == 0) { as_[tid >> 6] = s; aq_[tid >> 6] = q; }
  __syncthreads();
  s = as_[0] + as_[1] + as_[2] + as_[3];
  q = aq_[0] + aq_[1] + aq_[2] + aq_[3];
  float mu = s * (1.0f / 768.0f);
  float var = q * (1.0f / 768.0f) - mu * mu;
  float rs = rsqrtf(var + 1e-5f);
  ushortT* orow = out + base;
  orow[tid]       = f2b((v0 - mu) * rs * b2f(g[tid])       + b2f(bb[tid]));
  orow[tid + 256] = f2b((v1 - mu) * rs * b2f(g[tid + 256]) + b2f(bb[tid + 256]));
  orow[tid + 512] = f2b((v2 - mu) * rs * b2f(g[tid + 512]) + b2f(bb[tid + 512]));
}

// ---------------------------------------------------------------- GEMM
// C[M,N] = A[M,K] @ Bt[N,K]^T + bias. BM=128, BK=32, 256 thr (4 waves).
// BN=256: wave grid 1x4 (per-wave 128x64, MI=8,NI=4), 2 phases/K-tile.
// BN=128: wave grid 2x2 (per-wave 64x64,  MI=4,NI=4), 1 phase/K-tile.
// 3-slot LDS ring; stage tile t+2 during t; counted end-of-tile vmcnt.
// EPI: 0 bias->bf16 | 1 bias+gelu->bf16 | 2 bias+res(flag dtype)->fp32
//      3 bias+res(fp32)->flag-dtype out | 5 qkv: Q/K->out, V->res
//      (transposed vt[(b*12+h)*64+d][t], 8B RNE packs)
template <int EPI, int BN>
__global__ __launch_bounds__(256, 2) void gemm_8p(
    const ushortT* __restrict__ A, const ushortT* __restrict__ Bt,
    const ushortT* __restrict__ bias, const void* __restrict__ res,
    void* __restrict__ out, int N, int K, int lda, int nbm, int nbn,
    const int* __restrict__ flag) {
  constexpr int MI = (BN == 256) ? 8 : 4;
  constexpr int NI = 4;
  __shared__ ushortT As3[3][128 * 32];
  __shared__ ushortT Bs3[3][BN * 32];
  int fl = (EPI == 2 || EPI == 3) ? *flag : 0;
  int tid = threadIdx.x;
  int lane = tid & 63, wave = tid >> 6;
  int quad = lane >> 4, n = lane & 15;
  int wm, wn;
  if constexpr (BN == 256) { wm = 0; wn = wave * 64; }
  else { wm = (wave >> 1) * 64; wn = (wave & 1) * 64; }
  // XCD-locality decode
  int l = blockIdx.x;
  int xcd = l & 7, j = l >> 3;
  int m0 = (xcd * (nbm >> 3) + j / nbn) * 128;
  int n0 = (j % nbn) * BN;

  int trow = tid >> 2;
  int tc = (((tid & 3) ^ ((trow >> 1) & 3)) << 3);
  const ushortT* ga = A + (size_t)(m0 + trow) * lda + tc;
  const ushortT* gb = Bt + (size_t)(n0 + trow) * lda + tc;

  const int cs = (quad ^ ((n >> 1) & 3)) << 3;

  int kt = K >> 5;
  f32x4 acc[MI][NI] = {};

  auto stage = [&](int tt, int slot) {
    int k0 = tt << 5;
    ushortT* la = &As3[slot][0] + wave * 512;
    ushortT* lb = &Bs3[slot][0] + wave * 512;
    glds16(ga + k0, la);
    glds16(ga + (size_t)64 * lda + k0, la + 2048);
    glds16(gb + k0, lb);
    glds16(gb + (size_t)64 * lda + k0, lb + 2048);
    if constexpr (BN == 256) {
      glds16(gb + (size_t)128 * lda + k0, lb + 4096);
      glds16(gb + (size_t)192 * lda + k0, lb + 6144);
    }
  };

  stage(0, 0);
  stage(1, 1);
  if constexpr (BN == 256)
    asm volatile("s_waitcnt vmcnt(6)" ::: "memory");
  else
    asm volatile("s_waitcnt vmcnt(4)" ::: "memory");
  __builtin_amdgcn_s_barrier();

  int cur = 0;
  for (int t = 0; t < kt; ++t) {
    const ushortT* ca = &As3[cur][0];
    const ushortT* cb = &Bs3[cur][0];
    int nxt = cur + 2; if (nxt >= 3) nxt -= 3;
    bool pf = (t + 2) < kt;
    int pk0 = (t + 2) << 5;
    ushortT* la = &As3[nxt][0] + wave * 512;
    ushortT* lb = &Bs3[nxt][0] + wave * 512;

    bf16x8 af[4], bfr[NI];
#pragma unroll
    for (int i = 0; i < 4; ++i)
      af[i] = *(const bf16x8*)(ca + (wm + i * 16 + n) * 32 + cs);
#pragma unroll
    for (int i = 0; i < NI; ++i)
      bfr[i] = *(const bf16x8*)(cb + (wn + i * 16 + n) * 32 + cs);
    if (pf) {
      glds16(ga + pk0, la);
      glds16(ga + (size_t)64 * lda + pk0, la + 2048);
      glds16(gb + pk0, lb);
      if constexpr (BN == 128)
        glds16(gb + (size_t)64 * lda + pk0, lb + 2048);
    }
    __builtin_amdgcn_s_barrier();
    __builtin_amdgcn_s_setprio(1);
#pragma unroll
    for (int mi = 0; mi < 4; ++mi)
#pragma unroll
      for (int ni = 0; ni < NI; ++ni)
        acc[mi][ni] = MFMA16(af[mi], bfr[ni], acc[mi][ni]);
    __builtin_amdgcn_s_setprio(0);
    if constexpr (BN == 256) {
      __builtin_amdgcn_s_barrier();
#pragma unroll
      for (int i = 0; i < 4; ++i)
        af[i] = *(const bf16x8*)(ca + (64 + i * 16 + n) * 32 + cs);
      if (pf) {
        glds16(gb + (size_t)64 * lda + pk0, lb + 2048);
        glds16(gb + (size_t)128 * lda + pk0, lb + 4096);
        glds16(gb + (size_t)192 * lda + pk0, lb + 6144);
      }
      __builtin_amdgcn_s_barrier();
      __builtin_amdgcn_s_setprio(1);
#pragma unroll
      for (int mi = 0; mi < 4; ++mi)
#pragma unroll
        for (int ni = 0; ni < NI; ++ni)
          acc[4 + mi][ni] = MFMA16(af[mi], bfr[ni], acc[4 + mi][ni]);
      __builtin_amdgcn_s_setprio(0);
    }
    if (pf) {
      if constexpr (BN == 256)
        asm volatile("s_waitcnt vmcnt(6)" ::: "memory");
      else
        asm volatile("s_waitcnt vmcnt(4)" ::: "memory");
    } else {
      asm volatile("s_waitcnt vmcnt(0)" ::: "memory");
    }
    __builtin_amdgcn_s_barrier();

    cur = cur + 1; if (cur == 3) cur = 0;
  }

  // ---- epilogue
#pragma unroll
  for (int mi = 0; mi < MI; ++mi) {
#pragma unroll
    for (int ni = 0; ni < NI; ++ni) {
      int gc = n0 + wn + ni * 16 + n;
      float bv = b2f(bias[gc]);
      int gr0 = m0 + wm + mi * 16 + quad * 4;
      if constexpr (EPI == 5) {
        float v0 = acc[mi][ni][0] + bv;
        float v1 = acc[mi][ni][1] + bv;
        float v2 = acc[mi][ni][2] + bv;
        float v3 = acc[mi][ni][3] + bv;
        if (gc < 1536) {
          ushortT* o = (ushortT*)out;
          o[(size_t)(gr0 + 0) * N + gc] = f2b(v0);
          o[(size_t)(gr0 + 1) * N + gc] = f2b(v1);
          o[(size_t)(gr0 + 2) * N + gc] = f2b(v2);
          o[(size_t)(gr0 + 3) * N + gc] = f2b(v3);
        } else {
          int hh = (gc - 1536) >> 6, dd = (gc - 1536) & 63;
          int bb = gr0 >> 11, tin = gr0 & 2047;
          ushortT* vp = (ushortT*)res;
          uint2 o;
          o.x = (uintT)f2b(v0) | ((uintT)f2b(v1) << 16);
          o.y = (uintT)f2b(v2) | ((uintT)f2b(v3) << 16);
          *(uint2*)(vp + ((size_t)(bb * 12 + hh) * 64 + dd) * 2048 + tin) = o;
        }
      } else {
#pragma unroll
        for (int r = 0; r < 4; ++r) {
          size_t idx = (size_t)(gr0 + r) * N + gc;
          float v = acc[mi][ni][r] + bv;
          if constexpr (EPI == 1) {
            v = gelu_tanh(v);
            ((ushortT*)out)[idx] = f2b(v);
          } else if constexpr (EPI == 2) {
            v += fl ? ((const float*)res)[idx] : b2f(((const ushortT*)res)[idx]);
            ((float*)out)[idx] = v;
          } else if constexpr (EPI == 3) {
            v += ((const float*)res)[idx];
            if (fl) ((float*)out)[idx] = v;
            else    ((ushortT*)out)[idx] = f2b(v);
          } else {
            ((ushortT*)out)[idx] = f2b(v);
          }
        }
      }
    }
  }
}

// ---------------------------------------------------------------- attention
// Flash, causal, shared-staging: block pj stages k-tiles t=0..31-pj ONCE;
// each staged tile serves q-tile qtB=31-pj (always) and qtA=pj (t<=pj),
// with K/V fragments reused in-register for both. 4 waves x 16 q-rows per
// q-tile. S^T = K Q^T, O^T = V^T P^T, fixed-offset base-2 softmax.
// K/V staged via glds16 double buffer (XOR-swizzled source, linear dest);
// one __syncthreads per staged tile.
__global__ __launch_bounds__(256) void attn_kernel(
    const ushortT* __restrict__ qkv, const ushortT* __restrict__ vt,
    ushortT* __restrict__ y) {
  const int T = 2048, C3 = 2304;
  constexpr int LDP = 72;
  __shared__ ushortT Ks[2][64 * 64];
  __shared__ ushortT Vs[2][64 * 64];
  __shared__ ushortT Ps[4 * 16 * LDP];
  int bh = blockIdx.y;
  int b = bh / 12, h = bh % 12;
  int pj = blockIdx.x;  // 0..15
  int tid = threadIdx.x;
  int lane = tid & 63, wave = tid >> 6;
  int quad = lane >> 4, n = lane & 15, n7 = n & 7;

  const ushortT* base = qkv + (size_t)b * T * C3;
  const ushortT* kbase = base + 768 + h * 64;
  const ushortT* vbase = vt + (size_t)bh * 64 * T;
  ushortT* myP = Ps + wave * 16 * LDP;

  const float QS = 0.18033688011112042f;  // log2(e)/8
  const float MB = 20.0f;                 // fixed base-2 shift

  int qtA = pj, qtB = 31 - pj;
  int ntiles = 32 - pj;  // staged k-tiles 0..31-pj

  int srow = lane >> 3, scol = lane & 7;
  const ushortT* kg =
      kbase + (size_t)(wave * 16 + srow) * C3 + ((scol ^ srow) << 3);
  const ushortT* vg =
      vbase + (size_t)(wave * 16 + srow) * T + ((scol ^ srow) << 3);

  const int c0 = (quad ^ n7) << 3;
  const int c1 = ((4 + quad) ^ n7) << 3;

  // load both Q sets upfront (scaled to base-2 units)
  bf16x8 aqA[2], aqB[2];
  {
    const ushortT* qrA =
        base + (size_t)(qtA * 64 + wave * 16 + n) * C3 + h * 64 + quad * 8;
    const ushortT* qrB =
        base + (size_t)(qtB * 64 + wave * 16 + n) * C3 + h * 64 + quad * 8;
#pragma unroll
    for (int dh = 0; dh < 2; ++dh) {
      union { ushortT u[8]; bf16x8 v; } ta, tb;
#pragma unroll
      for (int j = 0; j < 8; ++j) {
        ta.u[j] = f2b(b2f(qrA[dh * 32 + j]) * QS);
        tb.u[j] = f2b(b2f(qrB[dh * 32 + j]) * QS);
      }
      aqA[dh] = ta.v;
      aqB[dh] = tb.v;
    }
  }
  f32x4 OtA[4] = {}, OtB[4] = {};
  float lA = 0.f, lB = 0.f;

  auto stage = [&](int kt_, int buf) {
    int kof = kt_ << 6;
    ushortT* lk = &Ks[buf][0] + wave * 1024;
    ushortT* lv = &Vs[buf][0] + wave * 1024;
    glds16(kg + (size_t)kof * C3, lk);
    glds16(kg + (size_t)(kof + 8) * C3, lk + 512);
    glds16(vg + kof, lv);
    glds16(vg + (size_t)8 * T + kof, lv + 512);
  };

  stage(0, 0);
  __syncthreads();  // emits vmcnt(0): tile 0 landed

  int cur = 0;
  for (int t = 0; t < ntiles; ++t) {
    if (t + 1 < ntiles) stage(t + 1, cur ^ 1);  // prefetch next
    const ushortT* ks = &Ks[cur][0];
    const ushortT* vs = &Vs[cur][0];
    bool doA = (t <= pj);

    // ---- K fragments (shared by both q-tiles)
    f32x4 StB[4], StA[4];
    {
      bf16x8 ka[4][2];
#pragma unroll
      for (int g = 0; g < 4; ++g) {
        ka[g][0] = *(const bf16x8*)(ks + (g * 16 + n) * 64 + c0);
        ka[g][1] = *(const bf16x8*)(ks + (g * 16 + n) * 64 + c1);
      }
#pragma unroll
      for (int g = 0; g < 4; ++g) {
        f32x4 z = {};
        z = MFMA16(ka[g][0], aqB[0], z);
        StB[g] = MFMA16(ka[g][1], aqB[1], z);
      }
      if (doA) {
#pragma unroll
        for (int g = 0; g < 4; ++g) {
          f32x4 z = {};
          z = MFMA16(ka[g][0], aqA[0], z);
          StA[g] = MFMA16(ka[g][1], aqA[1], z);
        }
      }
    }

    // ---- V fragments (shared)
    bf16x8 va[4][2];
#pragma unroll
    for (int dt = 0; dt < 4; ++dt) {
      va[dt][0] = *(const bf16x8*)(vs + (dt * 16 + n) * 64 + c0);
      va[dt][1] = *(const bf16x8*)(vs + (dt * 16 + n) * 64 + c1);
    }

    int lim = wave * 16 + n;

    // ---- B side (always). Diagonal at t == ntiles-1 (kt == qtB).
    if (t == ntiles - 1) {
#pragma unroll
      for (int g = 0; g < 4; ++g)
#pragma unroll
        for (int r = 0; r < 4; ++r)
          if (g * 16 + quad * 4 + r > lim) StB[g][r] = -1e30f;
    }
    {
      float ls = 0.f;
#pragma unroll
      for (int g = 0; g < 4; ++g) {
        float p0 = fast_exp2(StB[g][0] - MB);
        float p1 = fast_exp2(StB[g][1] - MB);
        float p2 = fast_exp2(StB[g][2] - MB);
        float p3 = fast_exp2(StB[g][3] - MB);
        ls += (p0 + p1) + (p2 + p3);
        uint2 pk;
        pk.x = pack_bf2(p0, p1);
        pk.y = pack_bf2(p2, p3);
        *(uint2*)(myP + n * LDP + g * 16 + quad * 4) = pk;
      }
      ls += __shfl_xor(ls, 16);
      ls += __shfl_xor(ls, 32);
      lB += ls;
      bf16x8 pb0 = *(const bf16x8*)(myP + n * LDP + quad * 8);
      bf16x8 pb1 = *(const bf16x8*)(myP + n * LDP + 32 + quad * 8);
#pragma unroll
      for (int dt = 0; dt < 4; ++dt) {
        OtB[dt] = MFMA16(va[dt][0], pb0, OtB[dt]);
        OtB[dt] = MFMA16(va[dt][1], pb1, OtB[dt]);
      }
    }

    // ---- A side (t <= pj). Diagonal at t == pj.
    if (doA) {
      if (t == pj) {
#pragma unroll
        for (int g = 0; g < 4; ++g)
#pragma unroll
          for (int r = 0; r < 4; ++r)
            if (g * 16 + quad * 4 + r > lim) StA[g][r] = -1e30f;
      }
      float ls = 0.f;
#pragma unroll
      for (int g = 0; g < 4; ++g) {
        float p0 = fast_exp2(StA[g][0] - MB);
        float p1 = fast_exp2(StA[g][1] - MB);
        float p2 = fast_exp2(StA[g][2] - MB);
        float p3 = fast_exp2(StA[g][3] - MB);
        ls += (p0 + p1) + (p2 + p3);
        uint2 pk;
        pk.x = pack_bf2(p0, p1);
        pk.y = pack_bf2(p2, p3);
        *(uint2*)(myP + n * LDP + g * 16 + quad * 4) = pk;
      }
      ls += __shfl_xor(ls, 16);
      ls += __shfl_xor(ls, 32);
      lA += ls;
      bf16x8 pb0 = *(const bf16x8*)(myP + n * LDP + quad * 8);
      bf16x8 pb1 = *(const bf16x8*)(myP + n * LDP + 32 + quad * 8);
#pragma unroll
      for (int dt = 0; dt < 4; ++dt) {
        OtA[dt] = MFMA16(va[dt][0], pb0, OtA[dt]);
        OtA[dt] = MFMA16(va[dt][1], pb1, OtA[dt]);
      }
    }

    __syncthreads();  // vmcnt(0): t+1 landed; all reads of buf[cur] done
    cur ^= 1;
  }

  // ---- epilogue: both q-tiles
  {
    float inv = 1.0f / lA;
    int qg = qtA * 64 + wave * 16 + n;
#pragma unroll
    for (int dt = 0; dt < 4; ++dt) {
      uint2 o;
      o.x = pack_bf2(OtA[dt][0] * inv, OtA[dt][1] * inv);
      o.y = pack_bf2(OtA[dt][2] * inv, OtA[dt][3] * inv);
      *(uint2*)(y + (size_t)(b * T + qg) * 768 + h * 64 + dt * 16 +
                quad * 4) = o;
    }
  }
  {
    float inv = 1.0f / lB;
    int qg = qtB * 64 + wave * 16 + n;
#pragma unroll
    for (int dt = 0; dt < 4; ++dt) {
      uint2 o;
      o.x = pack_bf2(OtB[dt][0] * inv, OtB[dt][1] * inv);
      o.y = pack_bf2(OtB[dt][2] * inv, OtB[dt][3] * inv);
      *(uint2*)(y + (size_t)(b * T + qg) * 768 + h * 64 + dt * 16 +
                quad * 4) = o;
    }
  }
}

// ---------------------------------------------------------------- launch
extern "C" void kernel_launch(void* const* d_in, const int* in_sizes, int n_in,
                              void* d_out, int out_size, void* d_ws,
                              size_t ws_size, hipStream_t stream) {
  (void)in_sizes; (void)n_in; (void)out_size; (void)ws_size;
  const void* x       = d_in[0];
  const void* w_attn  = d_in[3];
  const void* w_aproj = d_in[5];
  const void* w_fc    = d_in[9];
  const void* w_mproj = d_in[11];

  char* ws = (char*)d_ws;
  ushortT* h1  = (ushortT*)(ws);                 // [8192,768] bf16 (ln1 out)
  ushortT* qkv = (ushortT*)(ws + 12582912);      // [8192,2304] bf16
  ushortT* yb  = (ushortT*)(ws + 50331648);      // [8192,768] bf16; later h2
  float*   x1  = (float*)(ws + 62914560);        // [8192,768] fp32
  ushortT* fcg = (ushortT*)(ws + 88080384);      // [8192,3072] bf16
  ushortT* wT0 = (ushortT*)(ws + 138412032);     // w_attn^T  [2304,768]
  ushortT* wT1 = (ushortT*)(ws + 141950976);     // w_aproj^T [768,768]
  ushortT* wT2 = (ushortT*)(ws + 143130624);     // w_fc^T    [3072,768]
  ushortT* wT3 = (ushortT*)(ws + 147849216);     // w_mproj^T [768,3072]
  ushortT* pv  = (ushortT*)(ws + 152567808);     // packed vectors (bf16)
  int*     flag = (int*)(ws + 152600576);
  // vt: [48][64][2048] bf16 = 12.58 MB, lives in the fcg region (dead until
  // fc, which runs after attention). NOT h1 (live A-input of qkv GEMM).
  ushortT* vt  = fcg;
  ushortT* h2  = yb;   // yb dead after aproj GEMM

  const int O_LN1G = 0, O_LN1B = 768, O_BATT = 1536, O_BAPR = 3840,
            O_LN2G = 4608, O_LN2B = 5376, O_BFC = 6144, O_BMPR = 9216;

  VecArgs va;
  va.src[0] = d_in[1];  va.n[0] = 768;  va.dstoff[0] = O_LN1G;
  va.src[1] = d_in[2];  va.n[1] = 768;  va.dstoff[1] = O_LN1B;
  va.src[2] = d_in[4];  va.n[2] = 2304; va.dstoff[2] = O_BATT;
  va.src[3] = d_in[6];  va.n[3] = 768;  va.dstoff[3] = O_BAPR;
  va.src[4] = d_in[7];  va.n[4] = 768;  va.dstoff[4] = O_LN2G;
  va.src[5] = d_in[8];  va.n[5] = 768;  va.dstoff[5] = O_LN2B;
  va.src[6] = d_in[10]; va.n[6] = 3072; va.dstoff[6] = O_BFC;
  va.src[7] = d_in[12]; va.n[7] = 768;  va.dstoff[7] = O_BMPR;

  // fused prep: 4 transposes (6912) + 39 convert chunks + 8192 LN1 rows
  prep_kernel<<<15143, 256, 0, stream>>>(
      w_attn, w_aproj, w_fc, w_mproj, va, wT0, wT1, wT2, wT3, pv, flag,
      x, d_in[1], d_in[2], h1);

  // qkv (EPI=5): Q/K -> qkv, V -> vt transposed. 576 blocks.
  gemm_8p<5, 256><<<576, 256, 0, stream>>>(
      h1, wT0, pv + O_BATT, vt, qkv, 2304, 768, 768, 64, 9, flag);
  attn_kernel<<<dim3(16, 48), 256, 0, stream>>>(qkv, vt, yb);
  // aproj: 384 blocks
  gemm_8p<2, 128><<<384, 256, 0, stream>>>(
      yb, wT1, pv + O_BAPR, x, x1, 768, 768, 768, 64, 6, flag);
  ln_kernel<1><<<8192, 256, 0, stream>>>(x1, pv + O_LN2G, pv + O_LN2B, h2, flag);
  // fc: 768 blocks (fcg overwrites vt region — attn already done)
  gemm_8p<1, 256><<<768, 256, 0, stream>>>(
      h2, wT2, pv + O_BFC, nullptr, fcg, 3072, 768, 768, 64, 12, flag);
  // mproj: 384 blocks, K=3072 (EPI=3: +res x1 -> d_out)
  gemm_8p<3, 128><<<384, 256, 0, stream>>>(
      fcg, wT3, pv + O_BMPR, x1, d_out, 768, 3072, 3072, 64, 6, flag);
}

// Round 12
// 390.449 us; speedup vs baseline: 1.1552x; 1.0256x over previous
//
#include <hip/hip_runtime.h>

// GPT-2 block forward, MI355X/gfx950. B=4 T=2048 C=768 H=12 D=64; M=8192.
// R21 = R20 (best: 400.5 us) + prep transpose vectorization:
//   64x64 tiles (1728 blocks, was 6912 x 32x32), float4/ushort4 16B loads,
//   uint2 8B stores through [64][65] LDS (odd stride, conflict-free).
//   Converts + LN1 + local dtype detect unchanged.
// GEMMs: gemm_8p at the six-structure-validated shape ceiling (~550 TF).
// qkv EPI=5 writes V transposed to vt; attention = R20 shared-staging.
// 7 launches.

typedef unsigned short ushortT;
typedef unsigned int uintT;
typedef __attribute__((ext_vector_type(8))) __bf16 bf16x8;
typedef __attribute__((ext_vector_type(4))) float f32x4;

#define MFMA16(a, b, c) __builtin_amdgcn_mfma_f32_16x16x32_bf16(a, b, c, 0, 0, 0)

__device__ inline float b2f(ushortT u) {
  return __uint_as_float(((uintT)u) << 16);
}
__device__ inline ushortT f2b(float f) {  // round-to-nearest-even
  uintT x = __float_as_uint(f);
  uintT r = x + 0x7fffu + ((x >> 16) & 1u);
  return (ushortT)(r >> 16);
}
// pack two f32 -> two bf16 (RTZ) in one v_perm_b32
__device__ inline uintT pack_bf2(float a, float b) {
  return __builtin_amdgcn_perm(__float_as_uint(b), __float_as_uint(a),
                               0x07060302u);
}

__device__ inline float fast_exp2(float x) {
#if __has_builtin(__builtin_amdgcn_exp2f)
  return __builtin_amdgcn_exp2f(x);
#else
  return exp2f(x);
#endif
}

__device__ inline float gelu_tanh(float v) {
  float t = 0.7978845608028654f * (v + 0.044715f * v * v * v);
  return v / (1.0f + __expf(-2.0f * t));
}

// async 16B/lane global->LDS. LDS dest = wave-uniform base + lane*16.
__device__ __forceinline__ void glds16(const ushortT* g, ushortT* l) {
  __builtin_amdgcn_global_load_lds(
      (const __attribute__((address_space(1))) unsigned int*)(const void*)g,
      (__attribute__((address_space(3))) unsigned int*)(void*)l, 16, 0, 0);
}

// ------------------------------------------------------------- prep (fused)
// One kernel: 4 weight transposes (64x64 vectorized tiles) + 8 vector
// converts + flag + LN1. Per-block LOCAL dtype detect: 64 even-index
// bf16-view exponents of w_fc (fp32: P(all<150) ~ 4e-15; bf16 never >=150).
struct VecArgs {
  const void* src[8];
  int n[8];
  int dstoff[8];
};

__global__ __launch_bounds__(256) void prep_kernel(
    const void* __restrict__ w_attn, const void* __restrict__ w_aproj,
    const void* __restrict__ w_fc, const void* __restrict__ w_mproj,
    VecArgs va, ushortT* __restrict__ wT0, ushortT* __restrict__ wT1,
    ushortT* __restrict__ wT2, ushortT* __restrict__ wT3,
    ushortT* __restrict__ pv, int* __restrict__ flag,
    const void* __restrict__ x, const void* __restrict__ ln1g,
    const void* __restrict__ ln1b, ushortT* __restrict__ h1) {
  __shared__ int sfl;
  __shared__ ushortT tile[64][65];  // 8.3 K ushorts
  __shared__ float as_[4], aq_[4];
  int tid = threadIdx.x;
  {
    int crazy = 0;
    if (tid < 64) {
      uintT e = (((const ushortT*)w_fc)[2 * (tid * 64)] >> 7) & 0xFF;
      crazy = (e >= 150) ? 1 : 0;
    }
    unsigned long long m = __ballot(crazy != 0);
    if (tid == 0) sfl = (m != 0ull) ? 1 : 0;
    __syncthreads();
  }
  int fl = sfl;
  int b = (int)blockIdx.x;
  if (b == 0 && tid == 0) *flag = fl;

  // 64x64 transpose tiles: counts per weight (K/64 x N/64)
  const int T0 = 432;             // w_attn  K=768  N=2304 (12x36)
  const int T1 = T0 + 144;        // w_aproj K=768  N=768  (12x12)
  const int T2 = T1 + 576;        // w_fc    K=768  N=3072 (12x48)
  const int T3 = T2 + 576;        // w_mproj K=3072 N=768  (48x12) = 1728
  const int T4 = T3 + 39;         // vector converts (39 chunks)

  if (b >= T4) {
    // ---- LN1: row = b - T4 of x[8192][768] -> h1 (bf16)
    int row = b - T4;
    size_t base = (size_t)row * 768;
    const float* xf = (const float*)x;
    const ushortT* xb = (const ushortT*)x;
    float v0 = fl ? xf[base + tid]       : b2f(xb[base + tid]);
    float v1 = fl ? xf[base + tid + 256] : b2f(xb[base + tid + 256]);
    float v2 = fl ? xf[base + tid + 512] : b2f(xb[base + tid + 512]);
    float s = v0 + v1 + v2;
    float q = v0 * v0 + v1 * v1 + v2 * v2;
#pragma unroll
    for (int off = 32; off; off >>= 1) {
      s += __shfl_xor(s, off);
      q += __shfl_xor(q, off);
    }
    if ((tid & 63) == 0) { as_[tid >> 6] = s; aq_[tid >> 6] = q; }
    __syncthreads();
    s = as_[0] + as_[1] + as_[2] + as_[3];
    q = aq_[0] + aq_[1] + aq_[2] + aq_[3];
    float mu = s * (1.0f / 768.0f);
    float var = q * (1.0f / 768.0f) - mu * mu;
    float rs = rsqrtf(var + 1e-5f);
    const float* gf = (const float*)ln1g;
    const ushortT* gb_ = (const ushortT*)ln1g;
    const float* bf = (const float*)ln1b;
    const ushortT* bb_ = (const ushortT*)ln1b;
    ushortT* orow = h1 + base;
#pragma unroll
    for (int jj = 0; jj < 3; ++jj) {
      int c = tid + jj * 256;
      float gv = fl ? gf[c] : b2f(gb_[c]);
      float bv = fl ? bf[c] : b2f(bb_[c]);
      float vv = (jj == 0) ? v0 : (jj == 1) ? v1 : v2;
      orow[c] = f2b((vv - mu) * rs * gv + bv);
    }
    return;
  }

  if (b >= T3) {
    // vector converts: chunks of 256 elems across the 8 vectors
    int c = b - T3;
    int v = 0;
    for (;;) {
      int nch = (va.n[v] + 255) >> 8;
      if (c < nch) break;
      c -= nch; ++v;
    }
    int i = c * 256 + tid;
    if (i < va.n[v]) {
      float xx = fl ? ((const float*)va.src[v])[i]
                    : b2f(((const ushortT*)va.src[v])[i]);
      pv[va.dstoff[v] + i] = f2b(xx);
    }
    return;
  }

  // ---- 64x64 vectorized transpose
  const void* in = nullptr;
  ushortT* out = nullptr;
  int K = 0, N = 0, gx = 0, t = 0;
  if (b < T0)      { in = w_attn;  out = wT0; K = 768;  N = 2304; gx = 36; t = b; }
  else if (b < T1) { in = w_aproj; out = wT1; K = 768;  N = 768;  gx = 12; t = b - T0; }
  else if (b < T2) { in = w_fc;    out = wT2; K = 768;  N = 3072; gx = 48; t = b - T1; }
  else             { in = w_mproj; out = wT3; K = 3072; N = 768;  gx = 12; t = b - T2; }

  int n0 = (t % gx) * 64, k0 = (t / gx) * 64;
  int rr = tid >> 4;            // 0..15
  int cc = (tid & 15) << 2;     // 0,4,...,60
  // load: rows k0+rr+16s, cols n0+cc..cc+3 (16B)
#pragma unroll
  for (int s = 0; s < 4; ++s) {
    int r = rr + s * 16;
    size_t base = (size_t)(k0 + r) * N + n0 + cc;
    if (fl) {
      float4 v = *(const float4*)((const float*)in + base);
      tile[r][cc + 0] = f2b(v.x);
      tile[r][cc + 1] = f2b(v.y);
      tile[r][cc + 2] = f2b(v.z);
      tile[r][cc + 3] = f2b(v.w);
    } else {
      ushort4 v = *(const ushort4*)((const ushortT*)in + base);
      tile[r][cc + 0] = v.x;
      tile[r][cc + 1] = v.y;
      tile[r][cc + 2] = v.z;
      tile[r][cc + 3] = v.w;
    }
  }
  __syncthreads();
  // store: out rows n0+rr+16s, cols k0+cc..cc+3 (8B uint2)
#pragma unroll
  for (int s = 0; s < 4; ++s) {
    int r = rr + s * 16;
    uintT u0 = (uintT)tile[cc + 0][r] | ((uintT)tile[cc + 1][r] << 16);
    uintT u1 = (uintT)tile[cc + 2][r] | ((uintT)tile[cc + 3][r] << 16);
    uint2 o; o.x = u0; o.y = u1;
    *(uint2*)(out + (size_t)(n0 + r) * K + k0 + cc) = o;
  }
}

// ---------------------------------------------------------------- layernorm
template <int MODE>
__global__ __launch_bounds__(256) void ln_kernel(
    const void* __restrict__ xin, const ushortT* __restrict__ g,
    const ushortT* __restrict__ bb, ushortT* __restrict__ out,
    const int* __restrict__ flag) {
  const int C = 768;
  bool f32;
  if constexpr (MODE == 1) f32 = true; else f32 = (*flag != 0);
  size_t base = (size_t)blockIdx.x * C;
  int tid = threadIdx.x;
  const float* xf = (const float*)xin;
  const ushortT* xb = (const ushortT*)xin;
  float v0 = f32 ? xf[base + tid]       : b2f(xb[base + tid]);
  float v1 = f32 ? xf[base + tid + 256] : b2f(xb[base + tid + 256]);
  float v2 = f32 ? xf[base + tid + 512] : b2f(xb[base + tid + 512]);
  float s = v0 + v1 + v2;
  float q = v0 * v0 + v1 * v1 + v2 * v2;
#pragma unroll
  for (int off = 32; off; off >>= 1) {
    s += __shfl_xor(s, off);
    q += __shfl_xor(q, off);
  }
  __shared__ float as_[4], aq_[4];
  if ((tid & 63) == 0) { as_[tid >> 6] = s; aq_[tid >> 6] = q; }
  __syncthreads();
  s = as_[0] + as_[1] + as_[2] + as_[3];
  q = aq_[0] + aq_[1] + aq_[2] + aq_[3];
  float mu = s * (1.0f / 768.0f);
  float var = q * (1.0f / 768.0f) - mu * mu;
  float rs = rsqrtf(var + 1e-5f);
  ushortT* orow = out + base;
  orow[tid]       = f2b((v0 - mu) * rs * b2f(g[tid])       + b2f(bb[tid]));
  orow[tid + 256] = f2b((v1 - mu) * rs * b2f(g[tid + 256]) + b2f(bb[tid + 256]));
  orow[tid + 512] = f2b((v2 - mu) * rs * b2f(g[tid + 512]) + b2f(bb[tid + 512]));
}

// ---------------------------------------------------------------- GEMM
// C[M,N] = A[M,K] @ Bt[N,K]^T + bias. BM=128, BK=32, 256 thr (4 waves).
// BN=256: wave grid 1x4 (per-wave 128x64, MI=8,NI=4), 2 phases/K-tile.
// BN=128: wave grid 2x2 (per-wave 64x64,  MI=4,NI=4), 1 phase/K-tile.
// 3-slot LDS ring; stage tile t+2 during t; counted end-of-tile vmcnt.
// EPI: 0 bias->bf16 | 1 bias+gelu->bf16 | 2 bias+res(flag dtype)->fp32
//      3 bias+res(fp32)->flag-dtype out | 5 qkv: Q/K->out, V->res
//      (transposed vt[(b*12+h)*64+d][t], 8B RNE packs)
template <int EPI, int BN>
__global__ __launch_bounds__(256, 2) void gemm_8p(
    const ushortT* __restrict__ A, const ushortT* __restrict__ Bt,
    const ushortT* __restrict__ bias, const void* __restrict__ res,
    void* __restrict__ out, int N, int K, int lda, int nbm, int nbn,
    const int* __restrict__ flag) {
  constexpr int MI = (BN == 256) ? 8 : 4;
  constexpr int NI = 4;
  __shared__ ushortT As3[3][128 * 32];
  __shared__ ushortT Bs3[3][BN * 32];
  int fl = (EPI == 2 || EPI == 3) ? *flag : 0;
  int tid = threadIdx.x;
  int lane = tid & 63, wave = tid >> 6;
  int quad = lane >> 4, n = lane & 15;
  int wm, wn;
  if constexpr (BN == 256) { wm = 0; wn = wave * 64; }
  else { wm = (wave >> 1) * 64; wn = (wave & 1) * 64; }
  // XCD-locality decode
  int l = blockIdx.x;
  int xcd = l & 7, j = l >> 3;
  int m0 = (xcd * (nbm >> 3) + j / nbn) * 128;
  int n0 = (j % nbn) * BN;

  int trow = tid >> 2;
  int tc = (((tid & 3) ^ ((trow >> 1) & 3)) << 3);
  const ushortT* ga = A + (size_t)(m0 + trow) * lda + tc;
  const ushortT* gb = Bt + (size_t)(n0 + trow) * lda + tc;

  const int cs = (quad ^ ((n >> 1) & 3)) << 3;

  int kt = K >> 5;
  f32x4 acc[MI][NI] = {};

  auto stage = [&](int tt, int slot) {
    int k0 = tt << 5;
    ushortT* la = &As3[slot][0] + wave * 512;
    ushortT* lb = &Bs3[slot][0] + wave * 512;
    glds16(ga + k0, la);
    glds16(ga + (size_t)64 * lda + k0, la + 2048);
    glds16(gb + k0, lb);
    glds16(gb + (size_t)64 * lda + k0, lb + 2048);
    if constexpr (BN == 256) {
      glds16(gb + (size_t)128 * lda + k0, lb + 4096);
      glds16(gb + (size_t)192 * lda + k0, lb + 6144);
    }
  };

  stage(0, 0);
  stage(1, 1);
  if constexpr (BN == 256)
    asm volatile("s_waitcnt vmcnt(6)" ::: "memory");
  else
    asm volatile("s_waitcnt vmcnt(4)" ::: "memory");
  __builtin_amdgcn_s_barrier();

  int cur = 0;
  for (int t = 0; t < kt; ++t) {
    const ushortT* ca = &As3[cur][0];
    const ushortT* cb = &Bs3[cur][0];
    int nxt = cur + 2; if (nxt >= 3) nxt -= 3;
    bool pf = (t + 2) < kt;
    int pk0 = (t + 2) << 5;
    ushortT* la = &As3[nxt][0] + wave * 512;
    ushortT* lb = &Bs3[nxt][0] + wave * 512;

    bf16x8 af[4], bfr[NI];
#pragma unroll
    for (int i = 0; i < 4; ++i)
      af[i] = *(const bf16x8*)(ca + (wm + i * 16 + n) * 32 + cs);
#pragma unroll
    for (int i = 0; i < NI; ++i)
      bfr[i] = *(const bf16x8*)(cb + (wn + i * 16 + n) * 32 + cs);
    if (pf) {
      glds16(ga + pk0, la);
      glds16(ga + (size_t)64 * lda + pk0, la + 2048);
      glds16(gb + pk0, lb);
      if constexpr (BN == 128)
        glds16(gb + (size_t)64 * lda + pk0, lb + 2048);
    }
    __builtin_amdgcn_s_barrier();
    __builtin_amdgcn_s_setprio(1);
#pragma unroll
    for (int mi = 0; mi < 4; ++mi)
#pragma unroll
      for (int ni = 0; ni < NI; ++ni)
        acc[mi][ni] = MFMA16(af[mi], bfr[ni], acc[mi][ni]);
    __builtin_amdgcn_s_setprio(0);
    if constexpr (BN == 256) {
      __builtin_amdgcn_s_barrier();
#pragma unroll
      for (int i = 0; i < 4; ++i)
        af[i] = *(const bf16x8*)(ca + (64 + i * 16 + n) * 32 + cs);
      if (pf) {
        glds16(gb + (size_t)64 * lda + pk0, lb + 2048);
        glds16(gb + (size_t)128 * lda + pk0, lb + 4096);
        glds16(gb + (size_t)192 * lda + pk0, lb + 6144);
      }
      __builtin_amdgcn_s_barrier();
      __builtin_amdgcn_s_setprio(1);
#pragma unroll
      for (int mi = 0; mi < 4; ++mi)
#pragma unroll
        for (int ni = 0; ni < NI; ++ni)
          acc[4 + mi][ni] = MFMA16(af[mi], bfr[ni], acc[4 + mi][ni]);
      __builtin_amdgcn_s_setprio(0);
    }
    if (pf) {
      if constexpr (BN == 256)
        asm volatile("s_waitcnt vmcnt(6)" ::: "memory");
      else
        asm volatile("s_waitcnt vmcnt(4)" ::: "memory");
    } else {
      asm volatile("s_waitcnt vmcnt(0)" ::: "memory");
    }
    __builtin_amdgcn_s_barrier();

    cur = cur + 1; if (cur == 3) cur = 0;
  }

  // ---- epilogue
#pragma unroll
  for (int mi = 0; mi < MI; ++mi) {
#pragma unroll
    for (int ni = 0; ni < NI; ++ni) {
      int gc = n0 + wn + ni * 16 + n;
      float bv = b2f(bias[gc]);
      int gr0 = m0 + wm + mi * 16 + quad * 4;
      if constexpr (EPI == 5) {
        float v0 = acc[mi][ni][0] + bv;
        float v1 = acc[mi][ni][1] + bv;
        float v2 = acc[mi][ni][2] + bv;
        float v3 = acc[mi][ni][3] + bv;
        if (gc < 1536) {
          ushortT* o = (ushortT*)out;
          o[(size_t)(gr0 + 0) * N + gc] = f2b(v0);
          o[(size_t)(gr0 + 1) * N + gc] = f2b(v1);
          o[(size_t)(gr0 + 2) * N + gc] = f2b(v2);
          o[(size_t)(gr0 + 3) * N + gc] = f2b(v3);
        } else {
          int hh = (gc - 1536) >> 6, dd = (gc - 1536) & 63;
          int bb = gr0 >> 11, tin = gr0 & 2047;
          ushortT* vp = (ushortT*)res;
          uint2 o;
          o.x = (uintT)f2b(v0) | ((uintT)f2b(v1) << 16);
          o.y = (uintT)f2b(v2) | ((uintT)f2b(v3) << 16);
          *(uint2*)(vp + ((size_t)(bb * 12 + hh) * 64 + dd) * 2048 + tin) = o;
        }
      } else {
#pragma unroll
        for (int r = 0; r < 4; ++r) {
          size_t idx = (size_t)(gr0 + r) * N + gc;
          float v = acc[mi][ni][r] + bv;
          if constexpr (EPI == 1) {
            v = gelu_tanh(v);
            ((ushortT*)out)[idx] = f2b(v);
          } else if constexpr (EPI == 2) {
            v += fl ? ((const float*)res)[idx] : b2f(((const ushortT*)res)[idx]);
            ((float*)out)[idx] = v;
          } else if constexpr (EPI == 3) {
            v += ((const float*)res)[idx];
            if (fl) ((float*)out)[idx] = v;
            else    ((ushortT*)out)[idx] = f2b(v);
          } else {
            ((ushortT*)out)[idx] = f2b(v);
          }
        }
      }
    }
  }
}

// ---------------------------------------------------------------- attention
// Flash, causal, shared-staging (R20): block pj stages k-tiles t=0..31-pj
// ONCE; each tile serves q-tile qtB=31-pj (always) and qtA=pj (t<=pj),
// K/V fragments reused in-register for both. Fixed-offset base-2 softmax.
__global__ __launch_bounds__(256) void attn_kernel(
    const ushortT* __restrict__ qkv, const ushortT* __restrict__ vt,
    ushortT* __restrict__ y) {
  const int T = 2048, C3 = 2304;
  constexpr int LDP = 72;
  __shared__ ushortT Ks[2][64 * 64];
  __shared__ ushortT Vs[2][64 * 64];
  __shared__ ushortT Ps[4 * 16 * LDP];
  int bh = blockIdx.y;
  int b = bh / 12, h = bh % 12;
  int pj = blockIdx.x;  // 0..15
  int tid = threadIdx.x;
  int lane = tid & 63, wave = tid >> 6;
  int quad = lane >> 4, n = lane & 15, n7 = n & 7;

  const ushortT* base = qkv + (size_t)b * T * C3;
  const ushortT* kbase = base + 768 + h * 64;
  const ushortT* vbase = vt + (size_t)bh * 64 * T;
  ushortT* myP = Ps + wave * 16 * LDP;

  const float QS = 0.18033688011112042f;  // log2(e)/8
  const float MB = 20.0f;                 // fixed base-2 shift

  int qtA = pj, qtB = 31 - pj;
  int ntiles = 32 - pj;  // staged k-tiles 0..31-pj

  int srow = lane >> 3, scol = lane & 7;
  const ushortT* kg =
      kbase + (size_t)(wave * 16 + srow) * C3 + ((scol ^ srow) << 3);
  const ushortT* vg =
      vbase + (size_t)(wave * 16 + srow) * T + ((scol ^ srow) << 3);

  const int c0 = (quad ^ n7) << 3;
  const int c1 = ((4 + quad) ^ n7) << 3;

  // load both Q sets upfront (scaled to base-2 units)
  bf16x8 aqA[2], aqB[2];
  {
    const ushortT* qrA =
        base + (size_t)(qtA * 64 + wave * 16 + n) * C3 + h * 64 + quad * 8;
    const ushortT* qrB =
        base + (size_t)(qtB * 64 + wave * 16 + n) * C3 + h * 64 + quad * 8;
#pragma unroll
    for (int dh = 0; dh < 2; ++dh) {
      union { ushortT u[8]; bf16x8 v; } ta, tb;
#pragma unroll
      for (int j = 0; j < 8; ++j) {
        ta.u[j] = f2b(b2f(qrA[dh * 32 + j]) * QS);
        tb.u[j] = f2b(b2f(qrB[dh * 32 + j]) * QS);
      }
      aqA[dh] = ta.v;
      aqB[dh] = tb.v;
    }
  }
  f32x4 OtA[4] = {}, OtB[4] = {};
  float lA = 0.f, lB = 0.f;

  auto stage = [&](int kt_, int buf) {
    int kof = kt_ << 6;
    ushortT* lk = &Ks[buf][0] + wave * 1024;
    ushortT* lv = &Vs[buf][0] + wave * 1024;
    glds16(kg + (size_t)kof * C3, lk);
    glds16(kg + (size_t)(kof + 8) * C3, lk + 512);
    glds16(vg + kof, lv);
    glds16(vg + (size_t)8 * T + kof, lv + 512);
  };

  stage(0, 0);
  __syncthreads();  // emits vmcnt(0): tile 0 landed

  int cur = 0;
  for (int t = 0; t < ntiles; ++t) {
    if (t + 1 < ntiles) stage(t + 1, cur ^ 1);  // prefetch next
    const ushortT* ks = &Ks[cur][0];
    const ushortT* vs = &Vs[cur][0];
    bool doA = (t <= pj);

    // ---- K fragments (shared by both q-tiles)
    f32x4 StB[4], StA[4];
    {
      bf16x8 ka[4][2];
#pragma unroll
      for (int g = 0; g < 4; ++g) {
        ka[g][0] = *(const bf16x8*)(ks + (g * 16 + n) * 64 + c0);
        ka[g][1] = *(const bf16x8*)(ks + (g * 16 + n) * 64 + c1);
      }
#pragma unroll
      for (int g = 0; g < 4; ++g) {
        f32x4 z = {};
        z = MFMA16(ka[g][0], aqB[0], z);
        StB[g] = MFMA16(ka[g][1], aqB[1], z);
      }
      if (doA) {
#pragma unroll
        for (int g = 0; g < 4; ++g) {
          f32x4 z = {};
          z = MFMA16(ka[g][0], aqA[0], z);
          StA[g] = MFMA16(ka[g][1], aqA[1], z);
        }
      }
    }

    // ---- V fragments (shared)
    bf16x8 va[4][2];
#pragma unroll
    for (int dt = 0; dt < 4; ++dt) {
      va[dt][0] = *(const bf16x8*)(vs + (dt * 16 + n) * 64 + c0);
      va[dt][1] = *(const bf16x8*)(vs + (dt * 16 + n) * 64 + c1);
    }

    int lim = wave * 16 + n;

    // ---- B side (always). Diagonal at t == ntiles-1 (kt == qtB).
    if (t == ntiles - 1) {
#pragma unroll
      for (int g = 0; g < 4; ++g)
#pragma unroll
        for (int r = 0; r < 4; ++r)
          if (g * 16 + quad * 4 + r > lim) StB[g][r] = -1e30f;
    }
    {
      float ls = 0.f;
#pragma unroll
      for (int g = 0; g < 4; ++g) {
        float p0 = fast_exp2(StB[g][0] - MB);
        float p1 = fast_exp2(StB[g][1] - MB);
        float p2 = fast_exp2(StB[g][2] - MB);
        float p3 = fast_exp2(StB[g][3] - MB);
        ls += (p0 + p1) + (p2 + p3);
        uint2 pk;
        pk.x = pack_bf2(p0, p1);
        pk.y = pack_bf2(p2, p3);
        *(uint2*)(myP + n * LDP + g * 16 + quad * 4) = pk;
      }
      ls += __shfl_xor(ls, 16);
      ls += __shfl_xor(ls, 32);
      lB += ls;
      bf16x8 pb0 = *(const bf16x8*)(myP + n * LDP + quad * 8);
      bf16x8 pb1 = *(const bf16x8*)(myP + n * LDP + 32 + quad * 8);
#pragma unroll
      for (int dt = 0; dt < 4; ++dt) {
        OtB[dt] = MFMA16(va[dt][0], pb0, OtB[dt]);
        OtB[dt] = MFMA16(va[dt][1], pb1, OtB[dt]);
      }
    }

    // ---- A side (t <= pj). Diagonal at t == pj.
    if (doA) {
      if (t == pj) {
#pragma unroll
        for (int g = 0; g < 4; ++g)
#pragma unroll
          for (int r = 0; r < 4; ++r)
            if (g * 16 + quad * 4 + r > lim) StA[g][r] = -1e30f;
      }
      float ls = 0.f;
#pragma unroll
      for (int g = 0; g < 4; ++g) {
        float p0 = fast_exp2(StA[g][0] - MB);
        float p1 = fast_exp2(StA[g][1] - MB);
        float p2 = fast_exp2(StA[g][2] - MB);
        float p3 = fast_exp2(StA[g][3] - MB);
        ls += (p0 + p1) + (p2 + p3);
        uint2 pk;
        pk.x = pack_bf2(p0, p1);
        pk.y = pack_bf2(p2, p3);
        *(uint2*)(myP + n * LDP + g * 16 + quad * 4) = pk;
      }
      ls += __shfl_xor(ls, 16);
      ls += __shfl_xor(ls, 32);
      lA += ls;
      bf16x8 pb0 = *(const bf16x8*)(myP + n * LDP + quad * 8);
      bf16x8 pb1 = *(const bf16x8*)(myP + n * LDP + 32 + quad * 8);
#pragma unroll
      for (int dt = 0; dt < 4; ++dt) {
        OtA[dt] = MFMA16(va[dt][0], pb0, OtA[dt]);
        OtA[dt] = MFMA16(va[dt][1], pb1, OtA[dt]);
      }
    }

    __syncthreads();  // vmcnt(0): t+1 landed; all reads of buf[cur] done
    cur ^= 1;
  }

  // ---- epilogue: both q-tiles
  {
    float inv = 1.0f / lA;
    int qg = qtA * 64 + wave * 16 + n;
#pragma unroll
    for (int dt = 0; dt < 4; ++dt) {
      uint2 o;
      o.x = pack_bf2(OtA[dt][0] * inv, OtA[dt][1] * inv);
      o.y = pack_bf2(OtA[dt][2] * inv, OtA[dt][3] * inv);
      *(uint2*)(y + (size_t)(b * T + qg) * 768 + h * 64 + dt * 16 +
                quad * 4) = o;
    }
  }
  {
    float inv = 1.0f / lB;
    int qg = qtB * 64 + wave * 16 + n;
#pragma unroll
    for (int dt = 0; dt < 4; ++dt) {
      uint2 o;
      o.x = pack_bf2(OtB[dt][0] * inv, OtB[dt][1] * inv);
      o.y = pack_bf2(OtB[dt][2] * inv, OtB[dt][3] * inv);
      *(uint2*)(y + (size_t)(b * T + qg) * 768 + h * 64 + dt * 16 +
                quad * 4) = o;
    }
  }
}

// ---------------------------------------------------------------- launch
extern "C" void kernel_launch(void* const* d_in, const int* in_sizes, int n_in,
                              void* d_out, int out_size, void* d_ws,
                              size_t ws_size, hipStream_t stream) {
  (void)in_sizes; (void)n_in; (void)out_size; (void)ws_size;
  const void* x       = d_in[0];
  const void* w_attn  = d_in[3];
  const void* w_aproj = d_in[5];
  const void* w_fc    = d_in[9];
  const void* w_mproj = d_in[11];

  char* ws = (char*)d_ws;
  ushortT* h1  = (ushortT*)(ws);                 // [8192,768] bf16 (ln1 out)
  ushortT* qkv = (ushortT*)(ws + 12582912);      // [8192,2304] bf16
  ushortT* yb  = (ushortT*)(ws + 50331648);      // [8192,768] bf16; later h2
  float*   x1  = (float*)(ws + 62914560);        // [8192,768] fp32
  ushortT* fcg = (ushortT*)(ws + 88080384);      // [8192,3072] bf16
  ushortT* wT0 = (ushortT*)(ws + 138412032);     // w_attn^T  [2304,768]
  ushortT* wT1 = (ushortT*)(ws + 141950976);     // w_aproj^T [768,768]
  ushortT* wT2 = (ushortT*)(ws + 143130624);     // w_fc^T    [3072,768]
  ushortT* wT3 = (ushortT*)(ws + 147849216);     // w_mproj^T [768,3072]
  ushortT* pv  = (ushortT*)(ws + 152567808);     // packed vectors (bf16)
  int*     flag = (int*)(ws + 152600576);
  // vt: [48][64][2048] bf16 = 12.58 MB, lives in the fcg region (dead until
  // fc, which runs after attention). NOT h1 (live A-input of qkv GEMM).
  ushortT* vt  = fcg;
  ushortT* h2  = yb;   // yb dead after aproj GEMM

  const int O_LN1G = 0, O_LN1B = 768, O_BATT = 1536, O_BAPR = 3840,
            O_LN2G = 4608, O_LN2B = 5376, O_BFC = 6144, O_BMPR = 9216;

  VecArgs va;
  va.src[0] = d_in[1];  va.n[0] = 768;  va.dstoff[0] = O_LN1G;
  va.src[1] = d_in[2];  va.n[1] = 768;  va.dstoff[1] = O_LN1B;
  va.src[2] = d_in[4];  va.n[2] = 2304; va.dstoff[2] = O_BATT;
  va.src[3] = d_in[6];  va.n[3] = 768;  va.dstoff[3] = O_BAPR;
  va.src[4] = d_in[7];  va.n[4] = 768;  va.dstoff[4] = O_LN2G;
  va.src[5] = d_in[8];  va.n[5] = 768;  va.dstoff[5] = O_LN2B;
  va.src[6] = d_in[10]; va.n[6] = 3072; va.dstoff[6] = O_BFC;
  va.src[7] = d_in[12]; va.n[7] = 768;  va.dstoff[7] = O_BMPR;

  // fused prep: 4 transposes (1728 x 64x64) + 39 convert chunks + 8192 LN1
  prep_kernel<<<9959, 256, 0, stream>>>(
      w_attn, w_aproj, w_fc, w_mproj, va, wT0, wT1, wT2, wT3, pv, flag,
      x, d_in[1], d_in[2], h1);

  // qkv (EPI=5): Q/K -> qkv, V -> vt transposed. 576 blocks.
  gemm_8p<5, 256><<<576, 256, 0, stream>>>(
      h1, wT0, pv + O_BATT, vt, qkv, 2304, 768, 768, 64, 9, flag);
  attn_kernel<<<dim3(16, 48), 256, 0, stream>>>(qkv, vt, yb);
  // aproj: 384 blocks
  gemm_8p<2, 128><<<384, 256, 0, stream>>>(
      yb, wT1, pv + O_BAPR, x, x1, 768, 768, 768, 64, 6, flag);
  ln_kernel<1><<<8192, 256, 0, stream>>>(x1, pv + O_LN2G, pv + O_LN2B, h2, flag);
  // fc: 768 blocks (fcg overwrites vt region — attn already done)
  gemm_8p<1, 256><<<768, 256, 0, stream>>>(
      h2, wT2, pv + O_BFC, nullptr, fcg, 3072, 768, 768, 64, 12, flag);
  // mproj: 384 blocks, K=3072 (EPI=3: +res x1 -> d_out)
  gemm_8p<3, 128><<<384, 256, 0, stream>>>(
      fcg, wT3, pv + O_BMPR, x1, d_out, 768, 3072, 3072, 64, 6, flag);
}